// Round 23
// baseline (289.386 us; speedup 1.0000x reference)
//
#include <hip/hip_runtime.h>
#include <cstdint>
#include <cstddef>

typedef __attribute__((ext_vector_type(8))) short bf16x8;
typedef __attribute__((ext_vector_type(4))) short short4v;
typedef __attribute__((ext_vector_type(4))) float f32x4;
typedef __attribute__((ext_vector_type(16))) float f32x16;

__device__ __forceinline__ short f2b(float f) {
    unsigned u = __builtin_bit_cast(unsigned, f);
    u = (u + 0x7FFFu + ((u >> 16) & 1u)) >> 16;
    return (short)u;
}
__device__ __forceinline__ float b2f(short s) {
    unsigned u = ((unsigned)(unsigned short)s) << 16;
    return __builtin_bit_cast(float, u);
}

__device__ __forceinline__ void gload16(const short* g, short* l) {
    __builtin_amdgcn_global_load_lds(
        (const __attribute__((address_space(1))) unsigned int*)g,
        (__attribute__((address_space(3))) unsigned int*)l, 16, 0, 0);
}

// gelu via sigmoid form
__device__ __forceinline__ float gelu_fast(float g) {
    float g2 = g * g;
    float gp = g * (0.7978845608f + 0.0356774081f * g2);
    float t = exp2f(-2.885390082f * gp);
    return g / (1.f + t);
}

__device__ __forceinline__ int pn_ffp(int n) {
    int m = (n < 2048) ? n : (n - 2048);
    int gofs = (n < 2048) ? 0 : 32;
    int x = m >> 6, c = m & 63;
    return x * 128 + ((c >> 5) << 6) + gofs + (c & 31);
}

// ---------------- unified preprocessing (+ gn_stats merged)
struct PrepArgs {
    const float* src[12];
    short* dst[12];
    const float* kv;
    short* kvb;
    const float* fb;
    float* bp;
    const float* qin;
    const float* gng;
    const float* gnb;
    float* gnsc;
    float* gnsh;
};

__global__ __launch_bounds__(256) void prep(PrepArgs a) {
    int t = blockIdx.x;
    int tid = threadIdx.x;
    __shared__ float tile[32][33];
    if (t >= 6144) {
        if (t >= 6468) {  // gn_stats: 256 blocks
            int bb = (t - 6468) >> 5, gg = (t - 6468) & 31;
            const float4* src = (const float4*)(a.qin + ((size_t)(bb * 512 + gg * 16)) * 1024);
            float s = 0.f, s2 = 0.f;
#pragma unroll
            for (int i = 0; i < 16; ++i) {
                float4 v = src[tid + 256 * i];
                s += (v.x + v.y) + (v.z + v.w);
                s2 += (v.x * v.x + v.y * v.y) + (v.z * v.z + v.w * v.w);
            }
#pragma unroll
            for (int m = 1; m < 64; m <<= 1) {
                s += __shfl_xor(s, m);
                s2 += __shfl_xor(s2, m);
            }
            float* red = &tile[0][0];
            int wv = tid >> 6;
            if ((tid & 63) == 0) { red[wv] = s; red[4 + wv] = s2; }
            __syncthreads();
            if (tid < 16) {
                float S = red[0] + red[1] + red[2] + red[3];
                float S2 = red[4] + red[5] + red[6] + red[7];
                float mu = S * (1.f / 16384.f);
                float var = S2 * (1.f / 16384.f) - mu * mu;
                float rs = rsqrtf(var + 1e-6f);
                int c = gg * 16 + tid;
                float scale = rs * a.gng[c];
                a.gnsc[bb * 512 + c] = scale;
                a.gnsh[bb * 512 + c] = a.gnb[c] - mu * scale;
            }
            return;
        }
        if (t >= 6452) {  // permbias
            int n = (t - 6452) * 256 + tid;
            if (n < 4096) a.bp[pn_ffp(n)] = a.fb[n];
            return;
        }
        int idx = (t - 6144) * 256 + tid;
        if (idx >= 78848) return;
        const float4* s = (const float4*)a.kv + (size_t)idx * 2;
        float4 va = s[0], vb = s[1];
        bf16x8 w;
        w[0] = f2b(va.x); w[1] = f2b(va.y); w[2] = f2b(va.z); w[3] = f2b(va.w);
        w[4] = f2b(vb.x); w[5] = f2b(vb.y); w[6] = f2b(vb.z); w[7] = f2b(vb.w);
        *(bf16x8*)(a.kvb + (size_t)idx * 8) = w;
        return;
    }
    const int jstart[12] = {0, 256, 512, 768, 1024, 1280, 1536, 1792, 2304, 2816, 3072, 5120};
    const int jK[12] = {512, 512, 512, 512, 512, 512, 512, 1024, 1024, 512, 512, 2048};
    const int jN[12] = {512, 512, 512, 512, 512, 512, 512, 512, 512, 512, 4096, 512};
    int j = 11;
#pragma unroll
    for (int i = 11; i >= 1; --i)
        if (t < jstart[i]) j = i - 1;
    int tx = t - jstart[j];
    int K = jK[j], N = jN[j];
    int tn = N >> 5;
    int n0 = (tx % tn) * 32, k0 = (tx / tn) * 32;
    const float* w = a.src[j];
    short* wt = a.dst[j];
    bool perm = (j == 10);

    int cx = tid & 31, ty0 = tid >> 5;
#pragma unroll
    for (int i = 0; i < 4; ++i) {
        int r = ty0 + i * 8;
        tile[r][cx] = w[(size_t)(k0 + r) * N + n0 + cx];
    }
    __syncthreads();
    int r = tid >> 3;
    int kg = (tid & 7) * 4;
    int drow = perm ? pn_ffp(n0 + r) : (n0 + r);
    short4v o = {f2b(tile[kg][r]), f2b(tile[kg + 1][r]),
                 f2b(tile[kg + 2][r]), f2b(tile[kg + 3][r])};
    *(short4v*)&wt[(size_t)drow * K + k0 + kg] = o;
}

// ---------------- GroupNorm apply + transpose
__global__ __launch_bounds__(256) void gn_apply(const float* __restrict__ q,
                                                const float* __restrict__ sc,
                                                const float* __restrict__ sh,
                                                short* __restrict__ out) {
    __shared__ short tile[512][33];
    int b = blockIdx.x >> 5, st = blockIdx.x & 31;
    int s0 = st * 32;
    int sl = threadIdx.x & 31, cg = threadIdx.x >> 5;
    for (int c = cg; c < 512; c += 8) {
        float v = q[((size_t)(b * 512 + c)) * 1024 + s0 + sl];
        float y = v * sc[b * 512 + c] + sh[b * 512 + c];
        tile[c][sl] = f2b(y);
    }
    __syncthreads();
    int sr = threadIdx.x >> 3, ch = threadIdx.x & 7;
    short* orow = out + ((size_t)(b * 1024 + s0 + sr)) * 512;
    for (int c8 = ch * 64; c8 < ch * 64 + 64; c8 += 8) {
        bf16x8 o;
#pragma unroll
        for (int jj = 0; jj < 8; ++jj) o[jj] = tile[c8 + jj][sr];
        *(bf16x8*)&orow[c8] = o;
    }
}

// ---------------- LayerNorm, bf16 in/out
__global__ __launch_bounds__(256) void ln_rows(const short* __restrict__ x,
                                               const float* __restrict__ g,
                                               const float* __restrict__ bta,
                                               short* __restrict__ out) {
    int row = blockIdx.x * 4 + (threadIdx.x >> 6);
    int lane = threadIdx.x & 63;
    bf16x8 v8 = *(const bf16x8*)(x + (size_t)row * 512 + lane * 8);
    float v[8];
#pragma unroll
    for (int j = 0; j < 8; ++j) v[j] = b2f(v8[j]);
    float s = 0.f, s2 = 0.f;
#pragma unroll
    for (int j = 0; j < 8; ++j) { s += v[j]; s2 += v[j] * v[j]; }
#pragma unroll
    for (int m = 1; m < 64; m <<= 1) {
        s += __shfl_xor(s, m);
        s2 += __shfl_xor(s2, m);
    }
    float mu = s * (1.f / 512.f);
    float var = s2 * (1.f / 512.f) - mu * mu;
    float rs = rsqrtf(var + 1e-5f);
    float4 ga = ((const float4*)g)[lane * 2], gb = ((const float4*)g)[lane * 2 + 1];
    float4 ba = ((const float4*)bta)[lane * 2], bb = ((const float4*)bta)[lane * 2 + 1];
    bf16x8 o;
    o[0] = f2b((v[0] - mu) * rs * ga.x + ba.x);
    o[1] = f2b((v[1] - mu) * rs * ga.y + ba.y);
    o[2] = f2b((v[2] - mu) * rs * ga.z + ba.z);
    o[3] = f2b((v[3] - mu) * rs * ga.w + ba.w);
    o[4] = f2b((v[4] - mu) * rs * gb.x + bb.x);
    o[5] = f2b((v[5] - mu) * rs * gb.y + bb.y);
    o[6] = f2b((v[6] - mu) * rs * gb.z + bb.z);
    o[7] = f2b((v[7] - mu) * rs * gb.w + bb.w);
    *(bf16x8*)(out + (size_t)row * 512 + lane * 8) = o;
}

// ---------------- generic GEMM: RUNTIME K, unroll-by-3 body, compile-time BUF.
// Inner loop on mfma_f32_32x32x16_bf16 (higher FLOP/cyc, half the MFMA instrs).
// C-layout (verified): col=lane&31, row=(reg&3)+8*(reg>>2)+4*(lane>>5).
template <int BN>
__global__ __launch_bounds__(256, 1) void gemm_gl(
    const short* __restrict__ A, const short* __restrict__ BT,
    int M, int N, int K,
    const float* __restrict__ bias,
    const short* __restrict__ addSrcB,
    short* __restrict__ outB,
    const float* __restrict__ resid,
    float* __restrict__ outFinal,
    int mode) {
    constexpr int CB = BN / 64;              // col-blocks of 32 per wave
    constexpr int ASZ = 3 * 128 * 32;
    constexpr int BSZ = 3 * BN * 32;
    __shared__ __attribute__((aligned(16))) short smem[ASZ + BSZ];
    short* Asb = smem;
    short* Bsb = smem + ASZ;
    int tid = threadIdx.x;
    int wave = tid >> 6, lane = tid & 63;
    int wr = wave >> 1, wc = wave & 1;
    int m0 = blockIdx.y * 128, n0 = blockIdx.x * BN;
    f32x16 acc[2][CB];
#pragma unroll
    for (int i = 0; i < 2; ++i)
#pragma unroll
        for (int j = 0; j < CB; ++j)
#pragma unroll
            for (int e = 0; e < 16; ++e) acc[i][j][e] = 0.f;

    int srow = tid >> 2;
    int scg = (((tid & 3) ^ ((tid >> 3) & 3)) << 3);
    int ar0 = m0 + srow; if (ar0 >= M) ar0 = M - 1;
    int ar1 = m0 + 64 + srow; if (ar1 >= M) ar1 = M - 1;
    const short* ag0 = A + (size_t)ar0 * K + scg;
    const short* ag1 = A + (size_t)ar1 * K + scg;
    const short* bg0 = BT + (size_t)(n0 + srow) * K + scg;
    const short* bg1 = BT + (size_t)(n0 + 64 + srow) * K + scg;
    int nk = K >> 5;

    auto stage = [&](int buf) {
        gload16(ag0, &Asb[buf * 4096 + wave * 512]);
        gload16(ag1, &Asb[buf * 4096 + 2048 + wave * 512]);
        gload16(bg0, &Bsb[buf * (BN * 32) + wave * 512]);
        if constexpr (BN == 128) gload16(bg1, &Bsb[buf * 4096 + 2048 + wave * 512]);
        ag0 += 32; ag1 += 32; bg0 += 32; bg1 += 32;
    };
    stage(0);
    stage(1);

    int l31 = lane & 31, l5 = lane >> 5;

#define GL_STEP(KT, BUF)                                                          \
    {                                                                             \
        __builtin_amdgcn_sched_barrier(0);                                        \
        if ((KT) + 1 < nk) {                                                      \
            if constexpr (BN == 128)                                              \
                asm volatile("s_waitcnt vmcnt(4)" ::: "memory");                  \
            else                                                                  \
                asm volatile("s_waitcnt vmcnt(3)" ::: "memory");                  \
        } else {                                                                  \
            asm volatile("s_waitcnt vmcnt(0)" ::: "memory");                      \
        }                                                                         \
        __builtin_amdgcn_sched_barrier(0);                                        \
        __builtin_amdgcn_s_barrier();                                             \
        if ((KT) + 2 < nk) stage(((BUF) + 2) % 3);                                \
        bf16x8 af[2][2], bfr[CB][2];                                              \
        _Pragma("unroll") for (int rb = 0; rb < 2; ++rb)                          \
            _Pragma("unroll") for (int kh = 0; kh < 2; ++kh) {                    \
                int row = wr * 64 + rb * 32 + l31;                                \
                int c4 = kh * 2 + l5;                                             \
                af[rb][kh] = *(const bf16x8*)&Asb[(BUF) * 4096 + row * 32 +       \
                                                  ((c4 ^ ((row >> 1) & 3)) << 3)];\
            }                                                                     \
        _Pragma("unroll") for (int cb = 0; cb < CB; ++cb)                         \
            _Pragma("unroll") for (int kh = 0; kh < 2; ++kh) {                    \
                int rowB = wc * (BN / 2) + cb * 32 + l31;                         \
                int c4 = kh * 2 + l5;                                             \
                bfr[cb][kh] = *(const bf16x8*)&Bsb[(BUF) * (BN * 32) + rowB * 32 +\
                                                   ((c4 ^ ((rowB >> 1) & 3)) << 3)];\
            }                                                                     \
        _Pragma("unroll") for (int kh = 0; kh < 2; ++kh)                          \
            _Pragma("unroll") for (int rb = 0; rb < 2; ++rb)                      \
                _Pragma("unroll") for (int cb = 0; cb < CB; ++cb)                 \
                    acc[rb][cb] = __builtin_amdgcn_mfma_f32_32x32x16_bf16(        \
                        af[rb][kh], bfr[cb][kh], acc[rb][cb], 0, 0, 0);           \
    }

    for (int kt = 0; kt < nk; kt += 3) {
        GL_STEP(kt, 0);
        if (kt + 1 < nk) GL_STEP(kt + 1, 1);
        if (kt + 2 < nk) GL_STEP(kt + 2, 2);
    }
#undef GL_STEP

    if (mode == 1) {
#pragma unroll
        for (int rb = 0; rb < 2; ++rb)
#pragma unroll
            for (int cb = 0; cb < CB; ++cb)
#pragma unroll
                for (int rq = 0; rq < 4; ++rq) {
                    int mm0 = m0 + wr * 64 + rb * 32 + rq * 8 + 4 * l5;
                    int nn = n0 + wc * (BN / 2) + cb * 32 + l31;
                    int bb = mm0 >> 10, ss = mm0 & 1023;
                    size_t oi = ((size_t)(bb * 512 + nn)) * 1024 + ss;
                    float bv = bias ? bias[nn] : 0.f;
                    float4 rv = *(const float4*)&resid[oi];
                    float4 ov;
                    ov.x = acc[rb][cb][rq * 4 + 0] + bv + rv.x;
                    ov.y = acc[rb][cb][rq * 4 + 1] + bv + rv.y;
                    ov.z = acc[rb][cb][rq * 4 + 2] + bv + rv.z;
                    ov.w = acc[rb][cb][rq * 4 + 3] + bv + rv.w;
                    *(float4*)&outFinal[oi] = ov;
                }
        return;
    }
    {
        constexpr int EC = BN + 4;
        float* ef = (float*)smem;
#pragma unroll
        for (int h = 0; h < 2; ++h) {
            __syncthreads();
            if (wr == h) {
#pragma unroll
                for (int rb = 0; rb < 2; ++rb)
#pragma unroll
                    for (int cb = 0; cb < CB; ++cb)
#pragma unroll
                        for (int reg = 0; reg < 16; ++reg) {
                            int rloc = rb * 32 + (reg & 3) + 8 * (reg >> 2) + 4 * l5;
                            ef[rloc * EC + wc * (BN / 2) + cb * 32 + l31] =
                                acc[rb][cb][reg];
                        }
            }
            __syncthreads();
#pragma unroll
            for (int q = 0; q < BN / 16; ++q) {
                int idx = q * 256 + tid;
                int row = idx / (BN / 4);
                int cq = (idx % (BN / 4)) * 4;
                int mm = m0 + h * 64 + row;
                if (mm >= M) continue;
                int nn = n0 + cq;
                float4 v = *(float4*)&ef[row * EC + cq];
                if (bias) {
                    float4 b4 = *(const float4*)&bias[nn];
                    v.x += b4.x; v.y += b4.y; v.z += b4.z; v.w += b4.w;
                }
                size_t ig = (size_t)mm * N + nn;
                if (addSrcB) {
                    short4v a4 = *(const short4v*)&addSrcB[ig];
                    v.x += b2f(a4[0]); v.y += b2f(a4[1]);
                    v.z += b2f(a4[2]); v.w += b2f(a4[3]);
                }
                short4v o = {f2b(v.x), f2b(v.y), f2b(v.z), f2b(v.w)};
                *(short4v*)&outB[ig] = o;
            }
        }
    }
}

// ---------------- 8-wave ffp GEMM: BM=128, BN=256, fused GEGLU (32x32 MFMA).
__global__ __launch_bounds__(512, 1) void gemm256w(
    const short* __restrict__ A, const short* __restrict__ BT,
    int M, int N, int K,
    const float* __restrict__ bias,
    short* __restrict__ outB) {
    __shared__ __attribute__((aligned(16))) short smem[3 * 4096 + 3 * 8192];
    short* Asb = smem;
    short* Bsb = smem + 12288;
    int tid = threadIdx.x;
    int wave = tid >> 6, lane = tid & 63;
    int wrM = wave >> 2, wcN = wave & 3;
    int m0 = blockIdx.y * 128, n0 = blockIdx.x * 256;
    f32x16 acc[2][2];
#pragma unroll
    for (int i = 0; i < 2; ++i)
#pragma unroll
        for (int j = 0; j < 2; ++j)
#pragma unroll
            for (int e = 0; e < 16; ++e) acc[i][j][e] = 0.f;

    const short* gp[3];
    int ldsoff[3];
    bool isA[3];
#pragma unroll
    for (int s = 0; s < 3; ++s) {
        int qq = wave * 3 + s;
        bool a = qq < 8;
        int r = (a ? qq : qq - 8) * 16 + (lane >> 2);
        int sc = (((lane & 3) ^ ((r >> 1) & 3)) << 3);
        gp[s] = a ? (A + (size_t)(m0 + r) * K + sc)
                  : (BT + (size_t)(n0 + r) * K + sc);
        ldsoff[s] = (a ? qq : (qq - 8)) * 512;
        isA[s] = a;
    }
    int nk = K >> 5;
    auto stage = [&](int buf) {
#pragma unroll
        for (int s = 0; s < 3; ++s) {
            short* l = isA[s] ? &Asb[buf * 4096 + ldsoff[s]]
                              : &Bsb[buf * 8192 + ldsoff[s]];
            gload16(gp[s], l);
            gp[s] += 32;
        }
    };
    stage(0);
    stage(1);

    int l31 = lane & 31, l5 = lane >> 5;

#define W8_STEP(KT, BUF)                                                          \
    {                                                                             \
        __builtin_amdgcn_sched_barrier(0);                                        \
        if ((KT) + 1 < nk) {                                                      \
            asm volatile("s_waitcnt vmcnt(3)" ::: "memory");                      \
        } else {                                                                  \
            asm volatile("s_waitcnt vmcnt(0)" ::: "memory");                      \
        }                                                                         \
        __builtin_amdgcn_sched_barrier(0);                                        \
        __builtin_amdgcn_s_barrier();                                             \
        if ((KT) + 2 < nk) stage(((BUF) + 2) % 3);                                \
        bf16x8 af[2][2], bfr[2][2];                                               \
        _Pragma("unroll") for (int rb = 0; rb < 2; ++rb)                          \
            _Pragma("unroll") for (int kh = 0; kh < 2; ++kh) {                    \
                int row = wrM * 64 + rb * 32 + l31;                               \
                int c4 = kh * 2 + l5;                                             \
                af[rb][kh] = *(const bf16x8*)&Asb[(BUF) * 4096 + row * 32 +       \
                                                  ((c4 ^ ((row >> 1) & 3)) << 3)];\
            }                                                                     \
        _Pragma("unroll") for (int cb = 0; cb < 2; ++cb)                          \
            _Pragma("unroll") for (int kh = 0; kh < 2; ++kh) {                    \
                int rowB = wcN * 64 + cb * 32 + l31;                              \
                int c4 = kh * 2 + l5;                                             \
                bfr[cb][kh] = *(const bf16x8*)&Bsb[(BUF) * 8192 + rowB * 32 +     \
                                                   ((c4 ^ ((rowB >> 1) & 3)) << 3)];\
            }                                                                     \
        _Pragma("unroll") for (int kh = 0; kh < 2; ++kh)                          \
            _Pragma("unroll") for (int rb = 0; rb < 2; ++rb)                      \
                _Pragma("unroll") for (int cb = 0; cb < 2; ++cb)                  \
                    acc[rb][cb] = __builtin_amdgcn_mfma_f32_32x32x16_bf16(        \
                        af[rb][kh], bfr[cb][kh], acc[rb][cb], 0, 0, 0);           \
    }

    for (int kt = 0; kt < nk; kt += 3) {
        W8_STEP(kt, 0);
        if (kt + 1 < nk) W8_STEP(kt + 1, 1);
        if (kt + 2 < nk) W8_STEP(kt + 2, 2);
    }
#undef W8_STEP

    // fused GEGLU epilogue: cb=0 frag is 'a' slots, cb=1 is the paired gates.
    short* eb = smem;  // [128][136] bf16
    int xhalf = wcN >> 1, half = wcN & 1;
    int slotA = n0 + wcN * 64 + l31;
    float biasA = bias[slotA];
    float biasG = bias[slotA + 32];
    int col = xhalf * 64 + half * 32 + l31;
    __syncthreads();
#pragma unroll
    for (int rb = 0; rb < 2; ++rb)
#pragma unroll
        for (int reg = 0; reg < 16; ++reg) {
            int row = wrM * 64 + rb * 32 + (reg & 3) + 8 * (reg >> 2) + 4 * l5;
            float a = acc[rb][0][reg] + biasA;
            float gt = acc[rb][1][reg] + biasG;
            float ge = gelu_fast(gt);
            eb[row * 136 + col] = f2b(a * ge);
        }
    __syncthreads();
#pragma unroll
    for (int q = 0; q < 4; ++q) {
        int idx = q * 512 + tid;
        int row = idx >> 4, cg = (idx & 15) * 8;
        bf16x8 o = *(bf16x8*)&eb[row * 136 + cg];
        *(bf16x8*)&outB[(size_t)(m0 + row) * 2048 + blockIdx.x * 128 + cg] = o;
    }
}

// ---------------- MFMA flash attention, max-free softmax, async-staged K/V.
// Row-sum l via MFMA ones-B. XCD remap + setprio. (R18-verified, unchanged)
__global__ __launch_bounds__(256, 1) void attn_mfma(const short* __restrict__ qp,
                                                    const short* __restrict__ kp,
                                                    const short* __restrict__ vp,
                                                    short* __restrict__ op,
                                                    int kv_len, int kvBatchRows,
                                                    int qStride, int kvStride) {
    __shared__ __attribute__((aligned(16))) short Kt[64][72];
    __shared__ __attribute__((aligned(16))) short Vt[64][72];
    __shared__ __attribute__((aligned(16))) short Pt[4][2][16][72];
    int tid = threadIdx.x, w = tid >> 6, lane = tid & 63;
    int g = lane >> 4, c = lane & 15;
    int id = blockIdx.x;
    int xcd = id & 7, jj2 = id >> 3;
    int bh = xcd * 8 + (jj2 >> 3);
    int qtile = jj2 & 7;
    int b = bh >> 3, h = bh & 7;
    int q0 = qtile * 128 + w * 16;

    const float QS = 0.125f * 1.44269504f;
    bf16x8 qa[2][2];
#pragma unroll
    for (int qi = 0; qi < 2; ++qi) {
        const short* qbase = qp + ((size_t)(b * 1024 + q0 + qi * 64 + c)) * qStride + h * 64;
        bf16x8 qr0 = *(const bf16x8*)(qbase + g * 8);
        bf16x8 qr1 = *(const bf16x8*)(qbase + 32 + g * 8);
#pragma unroll
        for (int j = 0; j < 8; ++j) {
            qa[qi][0][j] = f2b(b2f(qr0[j]) * QS);
            qa[qi][1][j] = f2b(b2f(qr1[j]) * QS);
        }
    }
    bf16x8 vones;
#pragma unroll
    for (int j = 0; j < 8; ++j) vones[j] = (short)0x3F80;  // bf16 1.0

    f32x4 oac[2][4], oacl[2];
#pragma unroll
    for (int qi = 0; qi < 2; ++qi) {
#pragma unroll
        for (int dt = 0; dt < 4; ++dt) oac[qi][dt] = (f32x4){0.f, 0.f, 0.f, 0.f};
        oacl[qi] = (f32x4){0.f, 0.f, 0.f, 0.f};
    }

    int skey = tid & 63, sd0 = (tid >> 6) * 16;
    int ntile = (kv_len + 63) >> 6;
    size_t kvbase = (size_t)b * kvBatchRows;

    bf16x8 k0, k1, v0, v1;
    {
        int krow = skey < kv_len ? skey : kv_len - 1;
        const short* kpp = kp + (kvbase + krow) * kvStride + h * 64 + sd0;
        const short* vpp = vp + (kvbase + krow) * kvStride + h * 64 + sd0;
        k0 = *(const bf16x8*)kpp; k1 = *(const bf16x8*)(kpp + 8);
        v0 = *(const bf16x8*)vpp; v1 = *(const bf16x8*)(vpp + 8);
    }

    for (int kt = 0; kt < ntile; ++kt) {
        __syncthreads();
        *(bf16x8*)&Kt[skey][sd0] = k0;
        *(bf16x8*)&Kt[skey][sd0 + 8] = k1;
#pragma unroll
        for (int j = 0; j < 8; ++j) {
            Vt[sd0 + j][skey] = v0[j];
            Vt[sd0 + 8 + j][skey] = v1[j];
        }
        __syncthreads();
        if (kt + 1 < ntile) {
            int krow = (kt + 1) * 64 + skey;
            if (krow >= kv_len) krow = kv_len - 1;
            const short* kpp = kp + (kvbase + krow) * kvStride + h * 64 + sd0;
            const short* vpp = vp + (kvbase + krow) * kvStride + h * 64 + sd0;
            k0 = *(const bf16x8*)kpp; k1 = *(const bf16x8*)(kpp + 8);
            v0 = *(const bf16x8*)vpp; v1 = *(const bf16x8*)(vpp + 8);
        }

        f32x4 s[2][4];
        __builtin_amdgcn_s_setprio(1);
#pragma unroll
        for (int nt = 0; nt < 4; ++nt) {
            bf16x8 kb0 = *(const bf16x8*)&Kt[nt * 16 + c][g * 8];
            bf16x8 kb1 = *(const bf16x8*)&Kt[nt * 16 + c][32 + g * 8];
#pragma unroll
            for (int qi = 0; qi < 2; ++qi) {
                s[qi][nt] = __builtin_amdgcn_mfma_f32_16x16x32_bf16(
                    qa[qi][0], kb0, (f32x4){0.f, 0.f, 0.f, 0.f}, 0, 0, 0);
                s[qi][nt] = __builtin_amdgcn_mfma_f32_16x16x32_bf16(
                    qa[qi][1], kb1, s[qi][nt], 0, 0, 0);
            }
        }
        __builtin_amdgcn_s_setprio(0);
        if (kt * 64 + 64 > kv_len) {
#pragma unroll
            for (int nt = 0; nt < 4; ++nt) {
                bool valid = kt * 64 + nt * 16 + c < kv_len;
#pragma unroll
                for (int qi = 0; qi < 2; ++qi)
#pragma unroll
                    for (int r = 0; r < 4; ++r)
                        s[qi][nt][r] = valid ? exp2f(s[qi][nt][r]) : 0.f;
            }
        } else {
#pragma unroll
            for (int nt = 0; nt < 4; ++nt)
#pragma unroll
                for (int qi = 0; qi < 2; ++qi)
#pragma unroll
                    for (int r = 0; r < 4; ++r)
                        s[qi][nt][r] = exp2f(s[qi][nt][r]);
        }

        bf16x8 pa[2][2];
#pragma unroll
        for (int qi = 0; qi < 2; ++qi) {
#pragma unroll
            for (int nt = 0; nt < 4; ++nt)
#pragma unroll
                for (int r = 0; r < 4; ++r)
                    Pt[w][qi][4 * g + r][nt * 16 + c] = f2b(s[qi][nt][r]);
        }
#pragma unroll
        for (int qi = 0; qi < 2; ++qi) {
            pa[qi][0] = *(const bf16x8*)&Pt[w][qi][c][g * 8];
            pa[qi][1] = *(const bf16x8*)&Pt[w][qi][c][32 + g * 8];
        }
        __builtin_amdgcn_s_setprio(1);
#pragma unroll
        for (int dt = 0; dt < 4; ++dt) {
            bf16x8 vb0 = *(const bf16x8*)&Vt[dt * 16 + c][g * 8];
            bf16x8 vb1 = *(const bf16x8*)&Vt[dt * 16 + c][32 + g * 8];
#pragma unroll
            for (int qi = 0; qi < 2; ++qi) {
                oac[qi][dt] = __builtin_amdgcn_mfma_f32_16x16x32_bf16(pa[qi][0], vb0, oac[qi][dt], 0, 0, 0);
                oac[qi][dt] = __builtin_amdgcn_mfma_f32_16x16x32_bf16(pa[qi][1], vb1, oac[qi][dt], 0, 0, 0);
            }
        }
#pragma unroll
        for (int qi = 0; qi < 2; ++qi) {
            oacl[qi] = __builtin_amdgcn_mfma_f32_16x16x32_bf16(pa[qi][0], vones, oacl[qi], 0, 0, 0);
            oacl[qi] = __builtin_amdgcn_mfma_f32_16x16x32_bf16(pa[qi][1], vones, oacl[qi], 0, 0, 0);
        }
        __builtin_amdgcn_s_setprio(0);
    }

#pragma unroll
    for (int qi = 0; qi < 2; ++qi)
#pragma unroll
        for (int r = 0; r < 4; ++r) {
            float inv = 1.f / oacl[qi][r];
            short* orow = op + ((size_t)(b * 1024 + q0 + qi * 64 + 4 * g + r)) * 512 + h * 64;
#pragma unroll
            for (int dt = 0; dt < 4; ++dt)
                orow[dt * 16 + c] = f2b(oac[qi][dt][r] * inv);
        }
}

extern "C" void kernel_launch(void* const* d_in, const int* in_sizes, int n_in,
                              void* d_out, int out_size, void* d_ws, size_t ws_size,
                              hipStream_t stream) {
    (void)in_sizes; (void)n_in; (void)out_size; (void)ws_size;
    const float* q_in = (const float*)d_in[0];
    const float* kv_in = (const float*)d_in[1];
    const float* gn_g = (const float*)d_in[2];
    const float* gn_b = (const float*)d_in[3];
    const float* ln2_g = (const float*)d_in[4];
    const float* ln2_b = (const float*)d_in[5];
    const float* ln3_g = (const float*)d_in[6];
    const float* ln3_b = (const float*)d_in[7];
    const float* ln4_g = (const float*)d_in[8];
    const float* ln4_b = (const float*)d_in[9];
    const float* fc_in_w = (const float*)d_in[10];
    const float* fc_in_b = (const float*)d_in[11];
    const float* fc_out_w = (const float*)d_in[12];
    const float* fc_out_b = (const float*)d_in[13];
    const float* a1_qw = (const float*)d_in[14];
    const float* a1_kw = (const float*)d_in[15];
    const float* a1_vw = (const float*)d_in[16];
    const float* a1_ow = (const float*)d_in[17];
    const float* a1_ob = (const float*)d_in[18];
    const float* a2_qw = (const float*)d_in[19];
    const float* a2_kw = (const float*)d_in[20];
    const float* a2_vw = (const float*)d_in[21];
    const float* a2_ow = (const float*)d_in[22];
    const float* a2_ob = (const float*)d_in[23];
    const float* ffp_w = (const float*)d_in[24];
    const float* ffp_b = (const float*)d_in[25];
    const float* ffo_w = (const float*)d_in[26];
    const float* ffo_b = (const float*)d_in[27];
    float* out = (float*)d_out;

    char* p = (char*)d_ws;
    auto alloc = [&](size_t n) {
        char* r = p;
        p += (n + 255) & ~(size_t)255;
        return r;
    };
    short* wt_fci = (short*)alloc((size_t)512 * 512 * 2);
    short* wt_fco = (short*)alloc((size_t)512 * 512 * 2);
    short* wt_qkv = (short*)alloc((size_t)1536 * 512 * 2);
    short* wt_a1o = (short*)alloc((size_t)512 * 512 * 2);
    short* wt_a2q = (short*)alloc((size_t)512 * 512 * 2);
    short* wt_kv2 = (short*)alloc((size_t)1024 * 1024 * 2);
    short* wt_a2o = (short*)alloc((size_t)512 * 512 * 2);
    short* wt_ffp = (short*)alloc((size_t)4096 * 512 * 2);
    short* wt_ffo = (short*)alloc((size_t)512 * 2048 * 2);
    float* biasP = (float*)alloc((size_t)4096 * 4);
    short* xb = (short*)alloc((size_t)8192 * 512 * 2);
    short* tb = (short*)alloc((size_t)8192 * 512 * 2);
    short* qkvbuf = (short*)alloc((size_t)8192 * 1536 * 2);
    short* qbuf = (short*)alloc((size_t)8192 * 512 * 2);
    short* kvpbuf = (short*)alloc((size_t)616 * 1024 * 2);
    short* obuf = (short*)alloc((size_t)8192 * 512 * 2);
    short* kvb = (short*)alloc((size_t)616 * 1024 * 2);
    short* ggb = (short*)alloc((size_t)8192 * 2048 * 2);
    float* gnsc = (float*)alloc((size_t)8 * 512 * 4);
    float* gnsh = (float*)alloc((size_t)8 * 512 * 4);

    PrepArgs pa;
    pa.src[0] = fc_in_w;  pa.dst[0] = wt_fci;
    pa.src[1] = fc_out_w; pa.dst[1] = wt_fco;
    pa.src[2] = a1_qw;    pa.dst[2] = wt_qkv;
    pa.src[3] = a1_kw;    pa.dst[3] = wt_qkv + (size_t)512 * 512;
    pa.src[4] = a1_vw;    pa.dst[4] = wt_qkv + (size_t)1024 * 512;
    pa.src[5] = a1_ow;    pa.dst[5] = wt_a1o;
    pa.src[6] = a2_qw;    pa.dst[6] = wt_a2q;
    pa.src[7] = a2_kw;    pa.dst[7] = wt_kv2;
    pa.src[8] = a2_vw;    pa.dst[8] = wt_kv2 + (size_t)512 * 1024;
    pa.src[9] = a2_ow;    pa.dst[9] = wt_a2o;
    pa.src[10] = ffp_w;   pa.dst[10] = wt_ffp;
    pa.src[11] = ffo_w;   pa.dst[11] = wt_ffo;
    pa.kv = kv_in; pa.kvb = kvb; pa.fb = ffp_b; pa.bp = biasP;
    pa.qin = q_in; pa.gng = gn_g; pa.gnb = gn_b; pa.gnsc = gnsc; pa.gnsh = gnsh;
    prep<<<6724, 256, 0, stream>>>(pa);

    gn_apply<<<256, 256, 0, stream>>>(q_in, gnsc, gnsh, tb);
    gemm_gl<128><<<dim3(4, 64), 256, 0, stream>>>(
        tb, wt_fci, 8192, 512, 512, fc_in_b, nullptr, xb, nullptr, nullptr, 0);
    ln_rows<<<2048, 256, 0, stream>>>(xb, ln2_g, ln2_b, tb);
    gemm_gl<128><<<dim3(12, 64), 256, 0, stream>>>(
        tb, wt_qkv, 8192, 1536, 512, nullptr, nullptr, qkvbuf, nullptr, nullptr, 0);
    attn_mfma<<<512, 256, 0, stream>>>(qkvbuf, qkvbuf + 512, qkvbuf + 1024, obuf,
                                       1024, 1024, 1536, 1536);
    gemm_gl<128><<<dim3(4, 64), 256, 0, stream>>>(
        obuf, wt_a1o, 8192, 512, 512, a1_ob, xb, xb, nullptr, nullptr, 0);
    ln_rows<<<2048, 256, 0, stream>>>(xb, ln3_g, ln3_b, tb);
    gemm_gl<128><<<dim3(4, 64), 256, 0, stream>>>(
        tb, wt_a2q, 8192, 512, 512, nullptr, nullptr, qbuf, nullptr, nullptr, 0);
    gemm_gl<64><<<dim3(16, 5), 256, 0, stream>>>(
        kvb, wt_kv2, 616, 1024, 1024, nullptr, nullptr, kvpbuf, nullptr, nullptr, 0);
    attn_mfma<<<512, 256, 0, stream>>>(qbuf, kvpbuf, kvpbuf + 512, obuf,
                                       77, 77, 512, 1024);
    gemm_gl<128><<<dim3(4, 64), 256, 0, stream>>>(
        obuf, wt_a2o, 8192, 512, 512, a2_ob, xb, xb, nullptr, nullptr, 0);
    ln_rows<<<2048, 256, 0, stream>>>(xb, ln4_g, ln4_b, tb);
    gemm256w<<<dim3(16, 64), 512, 0, stream>>>(tb, wt_ffp, 8192, 4096, 512,
                                               biasP, ggb);
    gemm_gl<128><<<dim3(4, 64), 256, 0, stream>>>(
        ggb, wt_ffo, 8192, 512, 2048, ffo_b, xb, tb, nullptr, nullptr, 0);
    gemm_gl<128><<<dim3(4, 64), 256, 0, stream>>>(
        tb, wt_fco, 8192, 512, 512, fc_out_b, nullptr, nullptr, q_in, out, 1);
}

// Round 24
// 281.928 us; speedup vs baseline: 1.0265x; 1.0265x over previous
//
#include <hip/hip_runtime.h>
#include <cstdint>
#include <cstddef>

typedef __attribute__((ext_vector_type(8))) short bf16x8;
typedef __attribute__((ext_vector_type(4))) short short4v;
typedef __attribute__((ext_vector_type(4))) float f32x4;

__device__ __forceinline__ short f2b(float f) {
    unsigned u = __builtin_bit_cast(unsigned, f);
    u = (u + 0x7FFFu + ((u >> 16) & 1u)) >> 16;
    return (short)u;
}
__device__ __forceinline__ float b2f(short s) {
    unsigned u = ((unsigned)(unsigned short)s) << 16;
    return __builtin_bit_cast(float, u);
}

__device__ __forceinline__ void gload16(const short* g, short* l) {
    __builtin_amdgcn_global_load_lds(
        (const __attribute__((address_space(1))) unsigned int*)g,
        (__attribute__((address_space(3))) unsigned int*)l, 16, 0, 0);
}

// gelu via sigmoid form
__device__ __forceinline__ float gelu_fast(float g) {
    float g2 = g * g;
    float gp = g * (0.7978845608f + 0.0356774081f * g2);
    float t = exp2f(-2.885390082f * gp);
    return g / (1.f + t);
}

__device__ __forceinline__ int pn_ffp(int n) {
    int m = (n < 2048) ? n : (n - 2048);
    int gofs = (n < 2048) ? 0 : 32;
    int x = m >> 6, c = m & 63;
    return x * 128 + ((c >> 5) << 6) + gofs + (c & 31);
}

// ---------------- unified preprocessing (+ gn_stats merged)
struct PrepArgs {
    const float* src[12];
    short* dst[12];
    const float* kv;
    short* kvb;
    const float* fb;
    float* bp;
    const float* qin;
    const float* gng;
    const float* gnb;
    float* gnsc;
    float* gnsh;
};

__global__ __launch_bounds__(256) void prep(PrepArgs a) {
    int t = blockIdx.x;
    int tid = threadIdx.x;
    __shared__ float tile[32][33];
    if (t >= 6144) {
        if (t >= 6468) {  // gn_stats: 256 blocks
            int bb = (t - 6468) >> 5, gg = (t - 6468) & 31;
            const float4* src = (const float4*)(a.qin + ((size_t)(bb * 512 + gg * 16)) * 1024);
            float s = 0.f, s2 = 0.f;
#pragma unroll
            for (int i = 0; i < 16; ++i) {
                float4 v = src[tid + 256 * i];
                s += (v.x + v.y) + (v.z + v.w);
                s2 += (v.x * v.x + v.y * v.y) + (v.z * v.z + v.w * v.w);
            }
#pragma unroll
            for (int m = 1; m < 64; m <<= 1) {
                s += __shfl_xor(s, m);
                s2 += __shfl_xor(s2, m);
            }
            float* red = &tile[0][0];
            int wv = tid >> 6;
            if ((tid & 63) == 0) { red[wv] = s; red[4 + wv] = s2; }
            __syncthreads();
            if (tid < 16) {
                float S = red[0] + red[1] + red[2] + red[3];
                float S2 = red[4] + red[5] + red[6] + red[7];
                float mu = S * (1.f / 16384.f);
                float var = S2 * (1.f / 16384.f) - mu * mu;
                float rs = rsqrtf(var + 1e-6f);
                int c = gg * 16 + tid;
                float scale = rs * a.gng[c];
                a.gnsc[bb * 512 + c] = scale;
                a.gnsh[bb * 512 + c] = a.gnb[c] - mu * scale;
            }
            return;
        }
        if (t >= 6452) {  // permbias
            int n = (t - 6452) * 256 + tid;
            if (n < 4096) a.bp[pn_ffp(n)] = a.fb[n];
            return;
        }
        int idx = (t - 6144) * 256 + tid;
        if (idx >= 78848) return;
        const float4* s = (const float4*)a.kv + (size_t)idx * 2;
        float4 va = s[0], vb = s[1];
        bf16x8 w;
        w[0] = f2b(va.x); w[1] = f2b(va.y); w[2] = f2b(va.z); w[3] = f2b(va.w);
        w[4] = f2b(vb.x); w[5] = f2b(vb.y); w[6] = f2b(vb.z); w[7] = f2b(vb.w);
        *(bf16x8*)(a.kvb + (size_t)idx * 8) = w;
        return;
    }
    const int jstart[12] = {0, 256, 512, 768, 1024, 1280, 1536, 1792, 2304, 2816, 3072, 5120};
    const int jK[12] = {512, 512, 512, 512, 512, 512, 512, 1024, 1024, 512, 512, 2048};
    const int jN[12] = {512, 512, 512, 512, 512, 512, 512, 512, 512, 512, 4096, 512};
    int j = 11;
#pragma unroll
    for (int i = 11; i >= 1; --i)
        if (t < jstart[i]) j = i - 1;
    int tx = t - jstart[j];
    int K = jK[j], N = jN[j];
    int tn = N >> 5;
    int n0 = (tx % tn) * 32, k0 = (tx / tn) * 32;
    const float* w = a.src[j];
    short* wt = a.dst[j];
    bool perm = (j == 10);

    int cx = tid & 31, ty0 = tid >> 5;
#pragma unroll
    for (int i = 0; i < 4; ++i) {
        int r = ty0 + i * 8;
        tile[r][cx] = w[(size_t)(k0 + r) * N + n0 + cx];
    }
    __syncthreads();
    int r = tid >> 3;
    int kg = (tid & 7) * 4;
    int drow = perm ? pn_ffp(n0 + r) : (n0 + r);
    short4v o = {f2b(tile[kg][r]), f2b(tile[kg + 1][r]),
                 f2b(tile[kg + 2][r]), f2b(tile[kg + 3][r])};
    *(short4v*)&wt[(size_t)drow * K + k0 + kg] = o;
}

// ---------------- GroupNorm apply + transpose
__global__ __launch_bounds__(256) void gn_apply(const float* __restrict__ q,
                                                const float* __restrict__ sc,
                                                const float* __restrict__ sh,
                                                short* __restrict__ out) {
    __shared__ short tile[512][33];
    int b = blockIdx.x >> 5, st = blockIdx.x & 31;
    int s0 = st * 32;
    int sl = threadIdx.x & 31, cg = threadIdx.x >> 5;
    for (int c = cg; c < 512; c += 8) {
        float v = q[((size_t)(b * 512 + c)) * 1024 + s0 + sl];
        float y = v * sc[b * 512 + c] + sh[b * 512 + c];
        tile[c][sl] = f2b(y);
    }
    __syncthreads();
    int sr = threadIdx.x >> 3, ch = threadIdx.x & 7;
    short* orow = out + ((size_t)(b * 1024 + s0 + sr)) * 512;
    for (int c8 = ch * 64; c8 < ch * 64 + 64; c8 += 8) {
        bf16x8 o;
#pragma unroll
        for (int jj = 0; jj < 8; ++jj) o[jj] = tile[c8 + jj][sr];
        *(bf16x8*)&orow[c8] = o;
    }
}

// ---------------- LayerNorm, bf16 in/out
__global__ __launch_bounds__(256) void ln_rows(const short* __restrict__ x,
                                               const float* __restrict__ g,
                                               const float* __restrict__ bta,
                                               short* __restrict__ out) {
    int row = blockIdx.x * 4 + (threadIdx.x >> 6);
    int lane = threadIdx.x & 63;
    bf16x8 v8 = *(const bf16x8*)(x + (size_t)row * 512 + lane * 8);
    float v[8];
#pragma unroll
    for (int j = 0; j < 8; ++j) v[j] = b2f(v8[j]);
    float s = 0.f, s2 = 0.f;
#pragma unroll
    for (int j = 0; j < 8; ++j) { s += v[j]; s2 += v[j] * v[j]; }
#pragma unroll
    for (int m = 1; m < 64; m <<= 1) {
        s += __shfl_xor(s, m);
        s2 += __shfl_xor(s2, m);
    }
    float mu = s * (1.f / 512.f);
    float var = s2 * (1.f / 512.f) - mu * mu;
    float rs = rsqrtf(var + 1e-5f);
    float4 ga = ((const float4*)g)[lane * 2], gb = ((const float4*)g)[lane * 2 + 1];
    float4 ba = ((const float4*)bta)[lane * 2], bb = ((const float4*)bta)[lane * 2 + 1];
    bf16x8 o;
    o[0] = f2b((v[0] - mu) * rs * ga.x + ba.x);
    o[1] = f2b((v[1] - mu) * rs * ga.y + ba.y);
    o[2] = f2b((v[2] - mu) * rs * ga.z + ba.z);
    o[3] = f2b((v[3] - mu) * rs * ga.w + ba.w);
    o[4] = f2b((v[4] - mu) * rs * gb.x + bb.x);
    o[5] = f2b((v[5] - mu) * rs * gb.y + bb.y);
    o[6] = f2b((v[6] - mu) * rs * gb.z + bb.z);
    o[7] = f2b((v[7] - mu) * rs * gb.w + bb.w);
    *(bf16x8*)(out + (size_t)row * 512 + lane * 8) = o;
}

// ---------------- generic GEMM: RUNTIME K, unroll-by-3 body, compile-time BUF.
template <int BN>
__global__ __launch_bounds__(256, 1) void gemm_gl(
    const short* __restrict__ A, const short* __restrict__ BT,
    int M, int N, int K,
    const float* __restrict__ bias,
    const short* __restrict__ addSrcB,
    short* __restrict__ outB,
    const float* __restrict__ resid,
    float* __restrict__ outFinal,
    int mode) {
    constexpr int FJ = BN / 32;
    constexpr int ASZ = 3 * 128 * 32;
    constexpr int BSZ = 3 * BN * 32;
    __shared__ __attribute__((aligned(16))) short smem[ASZ + BSZ];
    short* Asb = smem;
    short* Bsb = smem + ASZ;
    int tid = threadIdx.x;
    int wave = tid >> 6, lane = tid & 63;
    int wr = wave >> 1, wc = wave & 1;
    int m0 = blockIdx.y * 128, n0 = blockIdx.x * BN;
    f32x4 acc[4][FJ];
#pragma unroll
    for (int i = 0; i < 4; ++i)
#pragma unroll
        for (int j = 0; j < FJ; ++j) acc[i][j] = (f32x4){0.f, 0.f, 0.f, 0.f};

    int srow = tid >> 2;
    int scg = (((tid & 3) ^ ((tid >> 3) & 3)) << 3);
    int ar0 = m0 + srow; if (ar0 >= M) ar0 = M - 1;
    int ar1 = m0 + 64 + srow; if (ar1 >= M) ar1 = M - 1;
    const short* ag0 = A + (size_t)ar0 * K + scg;
    const short* ag1 = A + (size_t)ar1 * K + scg;
    const short* bg0 = BT + (size_t)(n0 + srow) * K + scg;
    const short* bg1 = BT + (size_t)(n0 + 64 + srow) * K + scg;
    int nk = K >> 5;

    auto stage = [&](int buf) {
        gload16(ag0, &Asb[buf * 4096 + wave * 512]);
        gload16(ag1, &Asb[buf * 4096 + 2048 + wave * 512]);
        gload16(bg0, &Bsb[buf * (BN * 32) + wave * 512]);
        if constexpr (BN == 128) gload16(bg1, &Bsb[buf * 4096 + 2048 + wave * 512]);
        ag0 += 32; ag1 += 32; bg0 += 32; bg1 += 32;
    };
    stage(0);
    stage(1);

    int lr = lane & 15, g = lane >> 4;

#define GL_STEP(KT, BUF)                                                          \
    {                                                                             \
        __builtin_amdgcn_sched_barrier(0);                                        \
        if ((KT) + 1 < nk) {                                                      \
            if constexpr (BN == 128)                                              \
                asm volatile("s_waitcnt vmcnt(4)" ::: "memory");                  \
            else                                                                  \
                asm volatile("s_waitcnt vmcnt(3)" ::: "memory");                  \
        } else {                                                                  \
            asm volatile("s_waitcnt vmcnt(0)" ::: "memory");                      \
        }                                                                         \
        __builtin_amdgcn_sched_barrier(0);                                        \
        __builtin_amdgcn_s_barrier();                                             \
        if ((KT) + 2 < nk) stage(((BUF) + 2) % 3);                                \
        bf16x8 af[4], bfr[FJ];                                                    \
        _Pragma("unroll") for (int i = 0; i < 4; ++i) {                           \
            int row = wr * 64 + i * 16 + lr;                                      \
            af[i] = *(const bf16x8*)&Asb[(BUF) * 4096 + row * 32 +                \
                                         ((g ^ ((row >> 1) & 3)) << 3)];          \
        }                                                                         \
        _Pragma("unroll") for (int j = 0; j < FJ; ++j) {                          \
            int row = wc * (BN / 2) + j * 16 + lr;                                \
            bfr[j] = *(const bf16x8*)&Bsb[(BUF) * (BN * 32) + row * 32 +          \
                                          ((g ^ ((row >> 1) & 3)) << 3)];         \
        }                                                                         \
        _Pragma("unroll") for (int i = 0; i < 4; ++i)                             \
            _Pragma("unroll") for (int j = 0; j < FJ; ++j)                        \
                acc[i][j] = __builtin_amdgcn_mfma_f32_16x16x32_bf16(              \
                    af[i], bfr[j], acc[i][j], 0, 0, 0);                           \
    }

    for (int kt = 0; kt < nk; kt += 3) {
        GL_STEP(kt, 0);
        if (kt + 1 < nk) GL_STEP(kt + 1, 1);
        if (kt + 2 < nk) GL_STEP(kt + 2, 2);
    }
#undef GL_STEP

    int lq = lane >> 4;
    if (mode == 1) {
#pragma unroll
        for (int i = 0; i < 4; ++i)
#pragma unroll
            for (int j = 0; j < FJ; ++j) {
                int mm0 = m0 + wr * 64 + i * 16 + lq * 4;
                int nn = n0 + wc * (BN / 2) + j * 16 + lr;
                int bb = mm0 >> 10, ss = mm0 & 1023;
                size_t oi = ((size_t)(bb * 512 + nn)) * 1024 + ss;
                float bv = bias ? bias[nn] : 0.f;
                float4 rv = *(const float4*)&resid[oi];
                float4 ov;
                ov.x = acc[i][j][0] + bv + rv.x;
                ov.y = acc[i][j][1] + bv + rv.y;
                ov.z = acc[i][j][2] + bv + rv.z;
                ov.w = acc[i][j][3] + bv + rv.w;
                *(float4*)&outFinal[oi] = ov;
            }
        return;
    }
    {
        constexpr int EC = BN + 4;
        float* ef = (float*)smem;
#pragma unroll
        for (int h = 0; h < 2; ++h) {
            __syncthreads();
            if (wr == h) {
#pragma unroll
                for (int i = 0; i < 4; ++i)
#pragma unroll
                    for (int j = 0; j < FJ; ++j)
#pragma unroll
                        for (int r = 0; r < 4; ++r)
                            ef[(i * 16 + lq * 4 + r) * EC + wc * (BN / 2) + j * 16 + lr] =
                                acc[i][j][r];
            }
            __syncthreads();
#pragma unroll
            for (int q = 0; q < BN / 16; ++q) {
                int idx = q * 256 + tid;
                int row = idx / (BN / 4);
                int cq = (idx % (BN / 4)) * 4;
                int mm = m0 + h * 64 + row;
                if (mm >= M) continue;
                int nn = n0 + cq;
                float4 v = *(float4*)&ef[row * EC + cq];
                if (bias) {
                    float4 b4 = *(const float4*)&bias[nn];
                    v.x += b4.x; v.y += b4.y; v.z += b4.z; v.w += b4.w;
                }
                size_t ig = (size_t)mm * N + nn;
                if (addSrcB) {
                    short4v a4 = *(const short4v*)&addSrcB[ig];
                    v.x += b2f(a4[0]); v.y += b2f(a4[1]);
                    v.z += b2f(a4[2]); v.w += b2f(a4[3]);
                }
                short4v o = {f2b(v.x), f2b(v.y), f2b(v.z), f2b(v.w)};
                *(short4v*)&outB[ig] = o;
            }
        }
    }
}

// ---------------- 8-wave GEMM: BM=128, BN=256. RUNTIME K, compile-time BUF.
__global__ __launch_bounds__(512, 1) void gemm256w(
    const short* __restrict__ A, const short* __restrict__ BT,
    int M, int N, int K,
    const float* __restrict__ bias,
    const short* __restrict__ addSrcB,
    short* __restrict__ outB,
    int mode) {
    __shared__ __attribute__((aligned(16))) short smem[3 * 4096 + 3 * 8192];
    short* Asb = smem;
    short* Bsb = smem + 12288;
    int tid = threadIdx.x;
    int wave = tid >> 6, lane = tid & 63;
    int wrM = wave >> 2, wcN = wave & 3;
    int m0 = blockIdx.y * 128, n0 = blockIdx.x * 256;
    f32x4 acc[4][4];
#pragma unroll
    for (int i = 0; i < 4; ++i)
#pragma unroll
        for (int j = 0; j < 4; ++j) acc[i][j] = (f32x4){0.f, 0.f, 0.f, 0.f};

    const short* gp[3];
    int ldsoff[3];
    bool isA[3];
#pragma unroll
    for (int s = 0; s < 3; ++s) {
        int qq = wave * 3 + s;
        bool a = qq < 8;
        int r = (a ? qq : qq - 8) * 16 + (lane >> 2);
        int sc = (((lane & 3) ^ ((r >> 1) & 3)) << 3);
        gp[s] = a ? (A + (size_t)(m0 + r) * K + sc)
                  : (BT + (size_t)(n0 + r) * K + sc);
        ldsoff[s] = (a ? qq : (qq - 8)) * 512;
        isA[s] = a;
    }
    int nk = K >> 5;
    auto stage = [&](int buf) {
#pragma unroll
        for (int s = 0; s < 3; ++s) {
            short* l = isA[s] ? &Asb[buf * 4096 + ldsoff[s]]
                              : &Bsb[buf * 8192 + ldsoff[s]];
            gload16(gp[s], l);
            gp[s] += 32;
        }
    };
    stage(0);
    stage(1);

    int lr = lane & 15, g = lane >> 4;

#define W8_STEP(KT, BUF)                                                          \
    {                                                                             \
        __builtin_amdgcn_sched_barrier(0);                                        \
        if ((KT) + 1 < nk) {                                                      \
            asm volatile("s_waitcnt vmcnt(3)" ::: "memory");                      \
        } else {                                                                  \
            asm volatile("s_waitcnt vmcnt(0)" ::: "memory");                      \
        }                                                                         \
        __builtin_amdgcn_sched_barrier(0);                                        \
        __builtin_amdgcn_s_barrier();                                             \
        if ((KT) + 2 < nk) stage(((BUF) + 2) % 3);                                \
        bf16x8 af[4], bfr[4];                                                     \
        _Pragma("unroll") for (int i = 0; i < 4; ++i) {                           \
            int row = wrM * 64 + i * 16 + lr;                                     \
            af[i] = *(const bf16x8*)&Asb[(BUF) * 4096 + row * 32 +                \
                                         ((g ^ ((row >> 1) & 3)) << 3)];          \
        }                                                                         \
        _Pragma("unroll") for (int j = 0; j < 4; ++j) {                           \
            int row = wcN * 64 + j * 16 + lr;                                     \
            bfr[j] = *(const bf16x8*)&Bsb[(BUF) * 8192 + row * 32 +               \
                                          ((g ^ ((row >> 1) & 3)) << 3)];         \
        }                                                                         \
        _Pragma("unroll") for (int i = 0; i < 4; ++i)                             \
            _Pragma("unroll") for (int j = 0; j < 4; ++j)                         \
                acc[i][j] = __builtin_amdgcn_mfma_f32_16x16x32_bf16(              \
                    af[i], bfr[j], acc[i][j], 0, 0, 0);                           \
    }

    for (int kt = 0; kt < nk; kt += 3) {
        W8_STEP(kt, 0);
        if (kt + 1 < nk) W8_STEP(kt + 1, 1);
        if (kt + 2 < nk) W8_STEP(kt + 2, 2);
    }
#undef W8_STEP

    int lq = lane >> 4;
    if (mode == 2) {
        short* eb = smem;
        int xhalf = wcN >> 1, half = wcN & 1;
        __syncthreads();
#pragma unroll
        for (int i = 0; i < 4; ++i)
#pragma unroll
            for (int j = 0; j < 2; ++j)
#pragma unroll
                for (int r = 0; r < 4; ++r) {
                    int slot = n0 + wcN * 64 + j * 16 + lr;
                    float a = acc[i][j][r] + bias[slot];
                    float gt = acc[i][j + 2][r] + bias[slot + 32];
                    float ge = gelu_fast(gt);
                    int row = wrM * 64 + i * 16 + lq * 4 + r;
                    int col = xhalf * 64 + half * 32 + j * 16 + lr;
                    eb[row * 136 + col] = f2b(a * ge);
                }
        __syncthreads();
#pragma unroll
        for (int q = 0; q < 4; ++q) {
            int idx = q * 512 + tid;
            int row = idx >> 4, cg = (idx & 15) * 8;
            bf16x8 o = *(bf16x8*)&eb[row * 136 + cg];
            *(bf16x8*)&outB[(size_t)(m0 + row) * 2048 + blockIdx.x * 128 + cg] = o;
        }
        return;
    }
    {
        float* ef = (float*)smem;
#pragma unroll
        for (int h = 0; h < 2; ++h) {
            __syncthreads();
            if (wrM == h) {
#pragma unroll
                for (int i = 0; i < 4; ++i)
#pragma unroll
                    for (int j = 0; j < 4; ++j)
#pragma unroll
                        for (int r = 0; r < 4; ++r)
                            ef[(i * 16 + lq * 4 + r) * 260 + wcN * 64 + j * 16 + lr] =
                                acc[i][j][r];
            }
            __syncthreads();
#pragma unroll
            for (int q = 0; q < 8; ++q) {
                int idx = q * 512 + tid;
                int row = idx >> 6;
                int cq = (idx & 63) * 4;
                float4 v = *(float4*)&ef[row * 260 + cq];
                int nn = n0 + cq;
                if (bias) {
                    float4 b4 = *(const float4*)&bias[nn];
                    v.x += b4.x; v.y += b4.y; v.z += b4.z; v.w += b4.w;
                }
                size_t ig = (size_t)(m0 + h * 64 + row) * N + nn;
                if (addSrcB) {
                    short4v a4 = *(const short4v*)&addSrcB[ig];
                    v.x += b2f(a4[0]); v.y += b2f(a4[1]);
                    v.z += b2f(a4[2]); v.w += b2f(a4[3]);
                }
                short4v o = {f2b(v.x), f2b(v.y), f2b(v.z), f2b(v.w)};
                *(short4v*)&outB[ig] = o;
            }
        }
    }
}

// ---------------- MFMA flash attention, max-free softmax, async-staged K/V.
// Row-sum l via MFMA ones-B. XCD remap + setprio. (R18-verified)
__global__ __launch_bounds__(256, 1) void attn_mfma(const short* __restrict__ qp,
                                                    const short* __restrict__ kp,
                                                    const short* __restrict__ vp,
                                                    short* __restrict__ op,
                                                    int kv_len, int kvBatchRows,
                                                    int qStride, int kvStride) {
    __shared__ __attribute__((aligned(16))) short Kt[64][72];
    __shared__ __attribute__((aligned(16))) short Vt[64][72];
    __shared__ __attribute__((aligned(16))) short Pt[4][2][16][72];
    int tid = threadIdx.x, w = tid >> 6, lane = tid & 63;
    int g = lane >> 4, c = lane & 15;
    int id = blockIdx.x;
    int xcd = id & 7, jj2 = id >> 3;
    int bh = xcd * 8 + (jj2 >> 3);
    int qtile = jj2 & 7;
    int b = bh >> 3, h = bh & 7;
    int q0 = qtile * 128 + w * 16;

    const float QS = 0.125f * 1.44269504f;
    bf16x8 qa[2][2];
#pragma unroll
    for (int qi = 0; qi < 2; ++qi) {
        const short* qbase = qp + ((size_t)(b * 1024 + q0 + qi * 64 + c)) * qStride + h * 64;
        bf16x8 qr0 = *(const bf16x8*)(qbase + g * 8);
        bf16x8 qr1 = *(const bf16x8*)(qbase + 32 + g * 8);
#pragma unroll
        for (int j = 0; j < 8; ++j) {
            qa[qi][0][j] = f2b(b2f(qr0[j]) * QS);
            qa[qi][1][j] = f2b(b2f(qr1[j]) * QS);
        }
    }
    bf16x8 vones;
#pragma unroll
    for (int j = 0; j < 8; ++j) vones[j] = (short)0x3F80;  // bf16 1.0

    f32x4 oac[2][4], oacl[2];
#pragma unroll
    for (int qi = 0; qi < 2; ++qi) {
#pragma unroll
        for (int dt = 0; dt < 4; ++dt) oac[qi][dt] = (f32x4){0.f, 0.f, 0.f, 0.f};
        oacl[qi] = (f32x4){0.f, 0.f, 0.f, 0.f};
    }

    int skey = tid & 63, sd0 = (tid >> 6) * 16;
    int ntile = (kv_len + 63) >> 6;
    size_t kvbase = (size_t)b * kvBatchRows;

    bf16x8 k0, k1, v0, v1;
    {
        int krow = skey < kv_len ? skey : kv_len - 1;
        const short* kpp = kp + (kvbase + krow) * kvStride + h * 64 + sd0;
        const short* vpp = vp + (kvbase + krow) * kvStride + h * 64 + sd0;
        k0 = *(const bf16x8*)kpp; k1 = *(const bf16x8*)(kpp + 8);
        v0 = *(const bf16x8*)vpp; v1 = *(const bf16x8*)(vpp + 8);
    }

    for (int kt = 0; kt < ntile; ++kt) {
        __syncthreads();
        *(bf16x8*)&Kt[skey][sd0] = k0;
        *(bf16x8*)&Kt[skey][sd0 + 8] = k1;
#pragma unroll
        for (int j = 0; j < 8; ++j) {
            Vt[sd0 + j][skey] = v0[j];
            Vt[sd0 + 8 + j][skey] = v1[j];
        }
        __syncthreads();
        if (kt + 1 < ntile) {
            int krow = (kt + 1) * 64 + skey;
            if (krow >= kv_len) krow = kv_len - 1;
            const short* kpp = kp + (kvbase + krow) * kvStride + h * 64 + sd0;
            const short* vpp = vp + (kvbase + krow) * kvStride + h * 64 + sd0;
            k0 = *(const bf16x8*)kpp; k1 = *(const bf16x8*)(kpp + 8);
            v0 = *(const bf16x8*)vpp; v1 = *(const bf16x8*)(vpp + 8);
        }

        f32x4 s[2][4];
        __builtin_amdgcn_s_setprio(1);
#pragma unroll
        for (int nt = 0; nt < 4; ++nt) {
            bf16x8 kb0 = *(const bf16x8*)&Kt[nt * 16 + c][g * 8];
            bf16x8 kb1 = *(const bf16x8*)&Kt[nt * 16 + c][32 + g * 8];
#pragma unroll
            for (int qi = 0; qi < 2; ++qi) {
                s[qi][nt] = __builtin_amdgcn_mfma_f32_16x16x32_bf16(
                    qa[qi][0], kb0, (f32x4){0.f, 0.f, 0.f, 0.f}, 0, 0, 0);
                s[qi][nt] = __builtin_amdgcn_mfma_f32_16x16x32_bf16(
                    qa[qi][1], kb1, s[qi][nt], 0, 0, 0);
            }
        }
        __builtin_amdgcn_s_setprio(0);
        if (kt * 64 + 64 > kv_len) {
#pragma unroll
            for (int nt = 0; nt < 4; ++nt) {
                bool valid = kt * 64 + nt * 16 + c < kv_len;
#pragma unroll
                for (int qi = 0; qi < 2; ++qi)
#pragma unroll
                    for (int r = 0; r < 4; ++r)
                        s[qi][nt][r] = valid ? exp2f(s[qi][nt][r]) : 0.f;
            }
        } else {
#pragma unroll
            for (int nt = 0; nt < 4; ++nt)
#pragma unroll
                for (int qi = 0; qi < 2; ++qi)
#pragma unroll
                    for (int r = 0; r < 4; ++r)
                        s[qi][nt][r] = exp2f(s[qi][nt][r]);
        }

        bf16x8 pa[2][2];
#pragma unroll
        for (int qi = 0; qi < 2; ++qi) {
#pragma unroll
            for (int nt = 0; nt < 4; ++nt)
#pragma unroll
                for (int r = 0; r < 4; ++r)
                    Pt[w][qi][4 * g + r][nt * 16 + c] = f2b(s[qi][nt][r]);
        }
#pragma unroll
        for (int qi = 0; qi < 2; ++qi) {
            pa[qi][0] = *(const bf16x8*)&Pt[w][qi][c][g * 8];
            pa[qi][1] = *(const bf16x8*)&Pt[w][qi][c][32 + g * 8];
        }
        __builtin_amdgcn_s_setprio(1);
#pragma unroll
        for (int dt = 0; dt < 4; ++dt) {
            bf16x8 vb0 = *(const bf16x8*)&Vt[dt * 16 + c][g * 8];
            bf16x8 vb1 = *(const bf16x8*)&Vt[dt * 16 + c][32 + g * 8];
#pragma unroll
            for (int qi = 0; qi < 2; ++qi) {
                oac[qi][dt] = __builtin_amdgcn_mfma_f32_16x16x32_bf16(pa[qi][0], vb0, oac[qi][dt], 0, 0, 0);
                oac[qi][dt] = __builtin_amdgcn_mfma_f32_16x16x32_bf16(pa[qi][1], vb1, oac[qi][dt], 0, 0, 0);
            }
        }
#pragma unroll
        for (int qi = 0; qi < 2; ++qi) {
            oacl[qi] = __builtin_amdgcn_mfma_f32_16x16x32_bf16(pa[qi][0], vones, oacl[qi], 0, 0, 0);
            oacl[qi] = __builtin_amdgcn_mfma_f32_16x16x32_bf16(pa[qi][1], vones, oacl[qi], 0, 0, 0);
        }
        __builtin_amdgcn_s_setprio(0);
    }

#pragma unroll
    for (int qi = 0; qi < 2; ++qi)
#pragma unroll
        for (int r = 0; r < 4; ++r) {
            float inv = 1.f / oacl[qi][r];
            short* orow = op + ((size_t)(b * 1024 + q0 + qi * 64 + 4 * g + r)) * 512 + h * 64;
#pragma unroll
            for (int dt = 0; dt < 4; ++dt)
                orow[dt * 16 + c] = f2b(oac[qi][dt][r] * inv);
        }
}

extern "C" void kernel_launch(void* const* d_in, const int* in_sizes, int n_in,
                              void* d_out, int out_size, void* d_ws, size_t ws_size,
                              hipStream_t stream) {
    (void)in_sizes; (void)n_in; (void)out_size; (void)ws_size;
    const float* q_in = (const float*)d_in[0];
    const float* kv_in = (const float*)d_in[1];
    const float* gn_g = (const float*)d_in[2];
    const float* gn_b = (const float*)d_in[3];
    const float* ln2_g = (const float*)d_in[4];
    const float* ln2_b = (const float*)d_in[5];
    const float* ln3_g = (const float*)d_in[6];
    const float* ln3_b = (const float*)d_in[7];
    const float* ln4_g = (const float*)d_in[8];
    const float* ln4_b = (const float*)d_in[9];
    const float* fc_in_w = (const float*)d_in[10];
    const float* fc_in_b = (const float*)d_in[11];
    const float* fc_out_w = (const float*)d_in[12];
    const float* fc_out_b = (const float*)d_in[13];
    const float* a1_qw = (const float*)d_in[14];
    const float* a1_kw = (const float*)d_in[15];
    const float* a1_vw = (const float*)d_in[16];
    const float* a1_ow = (const float*)d_in[17];
    const float* a1_ob = (const float*)d_in[18];
    const float* a2_qw = (const float*)d_in[19];
    const float* a2_kw = (const float*)d_in[20];
    const float* a2_vw = (const float*)d_in[21];
    const float* a2_ow = (const float*)d_in[22];
    const float* a2_ob = (const float*)d_in[23];
    const float* ffp_w = (const float*)d_in[24];
    const float* ffp_b = (const float*)d_in[25];
    const float* ffo_w = (const float*)d_in[26];
    const float* ffo_b = (const float*)d_in[27];
    float* out = (float*)d_out;

    char* p = (char*)d_ws;
    auto alloc = [&](size_t n) {
        char* r = p;
        p += (n + 255) & ~(size_t)255;
        return r;
    };
    short* wt_fci = (short*)alloc((size_t)512 * 512 * 2);
    short* wt_fco = (short*)alloc((size_t)512 * 512 * 2);
    short* wt_qkv = (short*)alloc((size_t)1536 * 512 * 2);
    short* wt_a1o = (short*)alloc((size_t)512 * 512 * 2);
    short* wt_a2q = (short*)alloc((size_t)512 * 512 * 2);
    short* wt_kv2 = (short*)alloc((size_t)1024 * 1024 * 2);
    short* wt_a2o = (short*)alloc((size_t)512 * 512 * 2);
    short* wt_ffp = (short*)alloc((size_t)4096 * 512 * 2);
    short* wt_ffo = (short*)alloc((size_t)512 * 2048 * 2);
    float* biasP = (float*)alloc((size_t)4096 * 4);
    short* xb = (short*)alloc((size_t)8192 * 512 * 2);
    short* tb = (short*)alloc((size_t)8192 * 512 * 2);
    short* qkvbuf = (short*)alloc((size_t)8192 * 1536 * 2);
    short* qbuf = (short*)alloc((size_t)8192 * 512 * 2);
    short* kvpbuf = (short*)alloc((size_t)616 * 1024 * 2);
    short* obuf = (short*)alloc((size_t)8192 * 512 * 2);
    short* kvb = (short*)alloc((size_t)616 * 1024 * 2);
    short* ggb = (short*)alloc((size_t)8192 * 2048 * 2);
    float* gnsc = (float*)alloc((size_t)8 * 512 * 4);
    float* gnsh = (float*)alloc((size_t)8 * 512 * 4);

    PrepArgs pa;
    pa.src[0] = fc_in_w;  pa.dst[0] = wt_fci;
    pa.src[1] = fc_out_w; pa.dst[1] = wt_fco;
    pa.src[2] = a1_qw;    pa.dst[2] = wt_qkv;
    pa.src[3] = a1_kw;    pa.dst[3] = wt_qkv + (size_t)512 * 512;
    pa.src[4] = a1_vw;    pa.dst[4] = wt_qkv + (size_t)1024 * 512;
    pa.src[5] = a1_ow;    pa.dst[5] = wt_a1o;
    pa.src[6] = a2_qw;    pa.dst[6] = wt_a2q;
    pa.src[7] = a2_kw;    pa.dst[7] = wt_kv2;
    pa.src[8] = a2_vw;    pa.dst[8] = wt_kv2 + (size_t)512 * 1024;
    pa.src[9] = a2_ow;    pa.dst[9] = wt_a2o;
    pa.src[10] = ffp_w;   pa.dst[10] = wt_ffp;
    pa.src[11] = ffo_w;   pa.dst[11] = wt_ffo;
    pa.kv = kv_in; pa.kvb = kvb; pa.fb = ffp_b; pa.bp = biasP;
    pa.qin = q_in; pa.gng = gn_g; pa.gnb = gn_b; pa.gnsc = gnsc; pa.gnsh = gnsh;
    prep<<<6724, 256, 0, stream>>>(pa);

    gn_apply<<<256, 256, 0, stream>>>(q_in, gnsc, gnsh, tb);
    gemm_gl<128><<<dim3(4, 64), 256, 0, stream>>>(
        tb, wt_fci, 8192, 512, 512, fc_in_b, nullptr, xb, nullptr, nullptr, 0);
    ln_rows<<<2048, 256, 0, stream>>>(xb, ln2_g, ln2_b, tb);
    gemm_gl<128><<<dim3(12, 64), 256, 0, stream>>>(
        tb, wt_qkv, 8192, 1536, 512, nullptr, nullptr, qkvbuf, nullptr, nullptr, 0);
    attn_mfma<<<512, 256, 0, stream>>>(qkvbuf, qkvbuf + 512, qkvbuf + 1024, obuf,
                                       1024, 1024, 1536, 1536);
    gemm_gl<128><<<dim3(4, 64), 256, 0, stream>>>(
        obuf, wt_a1o, 8192, 512, 512, a1_ob, xb, xb, nullptr, nullptr, 0);
    ln_rows<<<2048, 256, 0, stream>>>(xb, ln3_g, ln3_b, tb);
    gemm_gl<128><<<dim3(4, 64), 256, 0, stream>>>(
        tb, wt_a2q, 8192, 512, 512, nullptr, nullptr, qbuf, nullptr, nullptr, 0);
    gemm_gl<64><<<dim3(16, 5), 256, 0, stream>>>(
        kvb, wt_kv2, 616, 1024, 1024, nullptr, nullptr, kvpbuf, nullptr, nullptr, 0);
    attn_mfma<<<512, 256, 0, stream>>>(qbuf, kvpbuf, kvpbuf + 512, obuf,
                                       77, 77, 512, 1024);
    gemm_gl<128><<<dim3(4, 64), 256, 0, stream>>>(
        obuf, wt_a2o, 8192, 512, 512, a2_ob, xb, xb, nullptr, nullptr, 0);
    ln_rows<<<2048, 256, 0, stream>>>(xb, ln4_g, ln4_b, tb);
    gemm256w<<<dim3(16, 64), 512, 0, stream>>>(tb, wt_ffp, 8192, 4096, 512,
                                               biasP, nullptr, ggb, 2);
    gemm_gl<128><<<dim3(4, 64), 256, 0, stream>>>(
        ggb, wt_ffo, 8192, 512, 2048, ffo_b, xb, tb, nullptr, nullptr, 0);
    gemm_gl<128><<<dim3(4, 64), 256, 0, stream>>>(
        tb, wt_fco, 8192, 512, 512, fc_out_b, nullptr, nullptr, q_in, out, 1);
}

// Round 25
// 273.795 us; speedup vs baseline: 1.0569x; 1.0297x over previous
//
#include <hip/hip_runtime.h>
#include <cstdint>
#include <cstddef>

typedef __attribute__((ext_vector_type(8))) short bf16x8;
typedef __attribute__((ext_vector_type(4))) short short4v;
typedef __attribute__((ext_vector_type(4))) float f32x4;

__device__ __forceinline__ short f2b(float f) {
    unsigned u = __builtin_bit_cast(unsigned, f);
    u = (u + 0x7FFFu + ((u >> 16) & 1u)) >> 16;
    return (short)u;
}
__device__ __forceinline__ float b2f(short s) {
    unsigned u = ((unsigned)(unsigned short)s) << 16;
    return __builtin_bit_cast(float, u);
}

__device__ __forceinline__ void gload16(const short* g, short* l) {
    __builtin_amdgcn_global_load_lds(
        (const __attribute__((address_space(1))) unsigned int*)g,
        (__attribute__((address_space(3))) unsigned int*)l, 16, 0, 0);
}

// gelu via sigmoid form
__device__ __forceinline__ float gelu_fast(float g) {
    float g2 = g * g;
    float gp = g * (0.7978845608f + 0.0356774081f * g2);
    float t = exp2f(-2.885390082f * gp);
    return g / (1.f + t);
}

__device__ __forceinline__ int pn_ffp(int n) {
    int m = (n < 2048) ? n : (n - 2048);
    int gofs = (n < 2048) ? 0 : 32;
    int x = m >> 6, c = m & 63;
    return x * 128 + ((c >> 5) << 6) + gofs + (c & 31);
}

// ---------------- unified preprocessing (+ gn_stats merged)
struct PrepArgs {
    const float* src[12];
    short* dst[12];
    const float* kv;
    short* kvb;
    const float* fb;
    float* bp;
    const float* qin;
    const float* gng;
    const float* gnb;
    float* gnsc;
    float* gnsh;
};

__global__ __launch_bounds__(256) void prep(PrepArgs a) {
    int t = blockIdx.x;
    int tid = threadIdx.x;
    __shared__ float tile[32][33];
    if (t >= 6144) {
        if (t >= 6468) {  // gn_stats: 256 blocks
            int bb = (t - 6468) >> 5, gg = (t - 6468) & 31;
            const float4* src = (const float4*)(a.qin + ((size_t)(bb * 512 + gg * 16)) * 1024);
            float s = 0.f, s2 = 0.f;
#pragma unroll
            for (int i = 0; i < 16; ++i) {
                float4 v = src[tid + 256 * i];
                s += (v.x + v.y) + (v.z + v.w);
                s2 += (v.x * v.x + v.y * v.y) + (v.z * v.z + v.w * v.w);
            }
#pragma unroll
            for (int m = 1; m < 64; m <<= 1) {
                s += __shfl_xor(s, m);
                s2 += __shfl_xor(s2, m);
            }
            float* red = &tile[0][0];
            int wv = tid >> 6;
            if ((tid & 63) == 0) { red[wv] = s; red[4 + wv] = s2; }
            __syncthreads();
            if (tid < 16) {
                float S = red[0] + red[1] + red[2] + red[3];
                float S2 = red[4] + red[5] + red[6] + red[7];
                float mu = S * (1.f / 16384.f);
                float var = S2 * (1.f / 16384.f) - mu * mu;
                float rs = rsqrtf(var + 1e-6f);
                int c = gg * 16 + tid;
                float scale = rs * a.gng[c];
                a.gnsc[bb * 512 + c] = scale;
                a.gnsh[bb * 512 + c] = a.gnb[c] - mu * scale;
            }
            return;
        }
        if (t >= 6452) {  // permbias
            int n = (t - 6452) * 256 + tid;
            if (n < 4096) a.bp[pn_ffp(n)] = a.fb[n];
            return;
        }
        int idx = (t - 6144) * 256 + tid;
        if (idx >= 78848) return;
        const float4* s = (const float4*)a.kv + (size_t)idx * 2;
        float4 va = s[0], vb = s[1];
        bf16x8 w;
        w[0] = f2b(va.x); w[1] = f2b(va.y); w[2] = f2b(va.z); w[3] = f2b(va.w);
        w[4] = f2b(vb.x); w[5] = f2b(vb.y); w[6] = f2b(vb.z); w[7] = f2b(vb.w);
        *(bf16x8*)(a.kvb + (size_t)idx * 8) = w;
        return;
    }
    const int jstart[12] = {0, 256, 512, 768, 1024, 1280, 1536, 1792, 2304, 2816, 3072, 5120};
    const int jK[12] = {512, 512, 512, 512, 512, 512, 512, 1024, 1024, 512, 512, 2048};
    const int jN[12] = {512, 512, 512, 512, 512, 512, 512, 512, 512, 512, 4096, 512};
    int j = 11;
#pragma unroll
    for (int i = 11; i >= 1; --i)
        if (t < jstart[i]) j = i - 1;
    int tx = t - jstart[j];
    int K = jK[j], N = jN[j];
    int tn = N >> 5;
    int n0 = (tx % tn) * 32, k0 = (tx / tn) * 32;
    const float* w = a.src[j];
    short* wt = a.dst[j];
    bool perm = (j == 10);

    int cx = tid & 31, ty0 = tid >> 5;
#pragma unroll
    for (int i = 0; i < 4; ++i) {
        int r = ty0 + i * 8;
        tile[r][cx] = w[(size_t)(k0 + r) * N + n0 + cx];
    }
    __syncthreads();
    int r = tid >> 3;
    int kg = (tid & 7) * 4;
    int drow = perm ? pn_ffp(n0 + r) : (n0 + r);
    short4v o = {f2b(tile[kg][r]), f2b(tile[kg + 1][r]),
                 f2b(tile[kg + 2][r]), f2b(tile[kg + 3][r])};
    *(short4v*)&wt[(size_t)drow * K + k0 + kg] = o;
}

// ---------------- GroupNorm apply + transpose
__global__ __launch_bounds__(256) void gn_apply(const float* __restrict__ q,
                                                const float* __restrict__ sc,
                                                const float* __restrict__ sh,
                                                short* __restrict__ out) {
    __shared__ short tile[512][33];
    int b = blockIdx.x >> 5, st = blockIdx.x & 31;
    int s0 = st * 32;
    int sl = threadIdx.x & 31, cg = threadIdx.x >> 5;
    for (int c = cg; c < 512; c += 8) {
        float v = q[((size_t)(b * 512 + c)) * 1024 + s0 + sl];
        float y = v * sc[b * 512 + c] + sh[b * 512 + c];
        tile[c][sl] = f2b(y);
    }
    __syncthreads();
    int sr = threadIdx.x >> 3, ch = threadIdx.x & 7;
    short* orow = out + ((size_t)(b * 1024 + s0 + sr)) * 512;
    for (int c8 = ch * 64; c8 < ch * 64 + 64; c8 += 8) {
        bf16x8 o;
#pragma unroll
        for (int jj = 0; jj < 8; ++jj) o[jj] = tile[c8 + jj][sr];
        *(bf16x8*)&orow[c8] = o;
    }
}

// ---------------- LayerNorm, bf16 in/out
__global__ __launch_bounds__(256) void ln_rows(const short* __restrict__ x,
                                               const float* __restrict__ g,
                                               const float* __restrict__ bta,
                                               short* __restrict__ out) {
    int row = blockIdx.x * 4 + (threadIdx.x >> 6);
    int lane = threadIdx.x & 63;
    bf16x8 v8 = *(const bf16x8*)(x + (size_t)row * 512 + lane * 8);
    float v[8];
#pragma unroll
    for (int j = 0; j < 8; ++j) v[j] = b2f(v8[j]);
    float s = 0.f, s2 = 0.f;
#pragma unroll
    for (int j = 0; j < 8; ++j) { s += v[j]; s2 += v[j] * v[j]; }
#pragma unroll
    for (int m = 1; m < 64; m <<= 1) {
        s += __shfl_xor(s, m);
        s2 += __shfl_xor(s2, m);
    }
    float mu = s * (1.f / 512.f);
    float var = s2 * (1.f / 512.f) - mu * mu;
    float rs = rsqrtf(var + 1e-5f);
    float4 ga = ((const float4*)g)[lane * 2], gb = ((const float4*)g)[lane * 2 + 1];
    float4 ba = ((const float4*)bta)[lane * 2], bb = ((const float4*)bta)[lane * 2 + 1];
    bf16x8 o;
    o[0] = f2b((v[0] - mu) * rs * ga.x + ba.x);
    o[1] = f2b((v[1] - mu) * rs * ga.y + ba.y);
    o[2] = f2b((v[2] - mu) * rs * ga.z + ba.z);
    o[3] = f2b((v[3] - mu) * rs * ga.w + ba.w);
    o[4] = f2b((v[4] - mu) * rs * gb.x + bb.x);
    o[5] = f2b((v[5] - mu) * rs * gb.y + bb.y);
    o[6] = f2b((v[6] - mu) * rs * gb.z + bb.z);
    o[7] = f2b((v[7] - mu) * rs * gb.w + bb.w);
    *(bf16x8*)(out + (size_t)row * 512 + lane * 8) = o;
}

// ---------------- generic GEMM body: RUNTIME K, unroll-by-3, compile-time BUF.
// Shared by gemm_gl (thin wrapper) and gemm_dual (a2q+kv2 merged dispatch).
template <int BN>
__device__ __forceinline__ void gemm_body(
    short* smem,
    const short* __restrict__ A, const short* __restrict__ BT,
    int M, int N, int K,
    const float* __restrict__ bias,
    const short* __restrict__ addSrcB,
    short* __restrict__ outB,
    const float* __restrict__ resid,
    float* __restrict__ outFinal,
    int mode, int bx, int by) {
    constexpr int FJ = BN / 32;
    constexpr int ASZ = 3 * 128 * 32;
    short* Asb = smem;
    short* Bsb = smem + ASZ;
    int tid = threadIdx.x;
    int wave = tid >> 6, lane = tid & 63;
    int wr = wave >> 1, wc = wave & 1;
    int m0 = by * 128, n0 = bx * BN;
    f32x4 acc[4][FJ];
#pragma unroll
    for (int i = 0; i < 4; ++i)
#pragma unroll
        for (int j = 0; j < FJ; ++j) acc[i][j] = (f32x4){0.f, 0.f, 0.f, 0.f};

    int srow = tid >> 2;
    int scg = (((tid & 3) ^ ((tid >> 3) & 3)) << 3);
    int ar0 = m0 + srow; if (ar0 >= M) ar0 = M - 1;
    int ar1 = m0 + 64 + srow; if (ar1 >= M) ar1 = M - 1;
    const short* ag0 = A + (size_t)ar0 * K + scg;
    const short* ag1 = A + (size_t)ar1 * K + scg;
    const short* bg0 = BT + (size_t)(n0 + srow) * K + scg;
    const short* bg1 = BT + (size_t)(n0 + 64 + srow) * K + scg;
    int nk = K >> 5;

    auto stage = [&](int buf) {
        gload16(ag0, &Asb[buf * 4096 + wave * 512]);
        gload16(ag1, &Asb[buf * 4096 + 2048 + wave * 512]);
        gload16(bg0, &Bsb[buf * (BN * 32) + wave * 512]);
        if constexpr (BN == 128) gload16(bg1, &Bsb[buf * 4096 + 2048 + wave * 512]);
        ag0 += 32; ag1 += 32; bg0 += 32; bg1 += 32;
    };
    stage(0);
    stage(1);

    int lr = lane & 15, g = lane >> 4;

#define GL_STEP(KT, BUF)                                                          \
    {                                                                             \
        __builtin_amdgcn_sched_barrier(0);                                        \
        if ((KT) + 1 < nk) {                                                      \
            if constexpr (BN == 128)                                              \
                asm volatile("s_waitcnt vmcnt(4)" ::: "memory");                  \
            else                                                                  \
                asm volatile("s_waitcnt vmcnt(3)" ::: "memory");                  \
        } else {                                                                  \
            asm volatile("s_waitcnt vmcnt(0)" ::: "memory");                      \
        }                                                                         \
        __builtin_amdgcn_sched_barrier(0);                                        \
        __builtin_amdgcn_s_barrier();                                             \
        if ((KT) + 2 < nk) stage(((BUF) + 2) % 3);                                \
        bf16x8 af[4], bfr[FJ];                                                    \
        _Pragma("unroll") for (int i = 0; i < 4; ++i) {                           \
            int row = wr * 64 + i * 16 + lr;                                      \
            af[i] = *(const bf16x8*)&Asb[(BUF) * 4096 + row * 32 +                \
                                         ((g ^ ((row >> 1) & 3)) << 3)];          \
        }                                                                         \
        _Pragma("unroll") for (int j = 0; j < FJ; ++j) {                          \
            int row = wc * (BN / 2) + j * 16 + lr;                                \
            bfr[j] = *(const bf16x8*)&Bsb[(BUF) * (BN * 32) + row * 32 +          \
                                          ((g ^ ((row >> 1) & 3)) << 3)];         \
        }                                                                         \
        _Pragma("unroll") for (int i = 0; i < 4; ++i)                             \
            _Pragma("unroll") for (int j = 0; j < FJ; ++j)                        \
                acc[i][j] = __builtin_amdgcn_mfma_f32_16x16x32_bf16(              \
                    af[i], bfr[j], acc[i][j], 0, 0, 0);                           \
    }

    for (int kt = 0; kt < nk; kt += 3) {
        GL_STEP(kt, 0);
        if (kt + 1 < nk) GL_STEP(kt + 1, 1);
        if (kt + 2 < nk) GL_STEP(kt + 2, 2);
    }
#undef GL_STEP

    int lq = lane >> 4;
    if (mode == 1) {
#pragma unroll
        for (int i = 0; i < 4; ++i)
#pragma unroll
            for (int j = 0; j < FJ; ++j) {
                int mm0 = m0 + wr * 64 + i * 16 + lq * 4;
                int nn = n0 + wc * (BN / 2) + j * 16 + lr;
                int bb = mm0 >> 10, ss = mm0 & 1023;
                size_t oi = ((size_t)(bb * 512 + nn)) * 1024 + ss;
                float bv = bias ? bias[nn] : 0.f;
                float4 rv = *(const float4*)&resid[oi];
                float4 ov;
                ov.x = acc[i][j][0] + bv + rv.x;
                ov.y = acc[i][j][1] + bv + rv.y;
                ov.z = acc[i][j][2] + bv + rv.z;
                ov.w = acc[i][j][3] + bv + rv.w;
                *(float4*)&outFinal[oi] = ov;
            }
        return;
    }
    {
        constexpr int EC = BN + 4;
        float* ef = (float*)smem;
#pragma unroll
        for (int h = 0; h < 2; ++h) {
            __syncthreads();
            if (wr == h) {
#pragma unroll
                for (int i = 0; i < 4; ++i)
#pragma unroll
                    for (int j = 0; j < FJ; ++j)
#pragma unroll
                        for (int r = 0; r < 4; ++r)
                            ef[(i * 16 + lq * 4 + r) * EC + wc * (BN / 2) + j * 16 + lr] =
                                acc[i][j][r];
            }
            __syncthreads();
#pragma unroll
            for (int q = 0; q < BN / 16; ++q) {
                int idx = q * 256 + tid;
                int row = idx / (BN / 4);
                int cq = (idx % (BN / 4)) * 4;
                int mm = m0 + h * 64 + row;
                if (mm >= M) continue;
                int nn = n0 + cq;
                float4 v = *(float4*)&ef[row * EC + cq];
                if (bias) {
                    float4 b4 = *(const float4*)&bias[nn];
                    v.x += b4.x; v.y += b4.y; v.z += b4.z; v.w += b4.w;
                }
                size_t ig = (size_t)mm * N + nn;
                if (addSrcB) {
                    short4v a4 = *(const short4v*)&addSrcB[ig];
                    v.x += b2f(a4[0]); v.y += b2f(a4[1]);
                    v.z += b2f(a4[2]); v.w += b2f(a4[3]);
                }
                short4v o = {f2b(v.x), f2b(v.y), f2b(v.z), f2b(v.w)};
                *(short4v*)&outB[ig] = o;
            }
        }
    }
}

template <int BN>
__global__ __launch_bounds__(256, 1) void gemm_gl(
    const short* __restrict__ A, const short* __restrict__ BT,
    int M, int N, int K,
    const float* __restrict__ bias,
    const short* __restrict__ addSrcB,
    short* __restrict__ outB,
    const float* __restrict__ resid,
    float* __restrict__ outFinal,
    int mode) {
    __shared__ __attribute__((aligned(16))) short smem[3 * 128 * 32 + 3 * BN * 32];
    gemm_body<BN>(smem, A, BT, M, N, K, bias, addSrcB, outB, resid, outFinal,
                  mode, blockIdx.x, blockIdx.y);
}

// merged a2q (256 blocks, BN=128) + kv2 (80 blocks, BN=64) — kv2 hides under
// a2q's shadow instead of a standalone 80-block dispatch idling 2/3 of the chip.
__global__ __launch_bounds__(256, 1) void gemm_dual(
    const short* __restrict__ A1, const short* __restrict__ B1,
    short* __restrict__ O1, int M1, int N1, int K1,
    const short* __restrict__ A2, const short* __restrict__ B2,
    short* __restrict__ O2, int M2, int N2, int K2) {
    __shared__ __attribute__((aligned(16))) short smem[3 * 128 * 32 + 3 * 128 * 32];
    int t = blockIdx.x;
    if (t < 80) {
        gemm_body<64>(smem, A2, B2, M2, N2, K2, nullptr, nullptr, O2,
                      nullptr, nullptr, 0, t & 15, t >> 4);
    } else {
        t -= 80;
        gemm_body<128>(smem, A1, B1, M1, N1, K1, nullptr, nullptr, O1,
                       nullptr, nullptr, 0, t & 3, t >> 2);
    }
}

// ---------------- 8-wave GEMM: BM=128, BN=256. RUNTIME K, compile-time BUF.
__global__ __launch_bounds__(512, 1) void gemm256w(
    const short* __restrict__ A, const short* __restrict__ BT,
    int M, int N, int K,
    const float* __restrict__ bias,
    const short* __restrict__ addSrcB,
    short* __restrict__ outB,
    int mode) {
    __shared__ __attribute__((aligned(16))) short smem[3 * 4096 + 3 * 8192];
    short* Asb = smem;
    short* Bsb = smem + 12288;
    int tid = threadIdx.x;
    int wave = tid >> 6, lane = tid & 63;
    int wrM = wave >> 2, wcN = wave & 3;
    int m0 = blockIdx.y * 128, n0 = blockIdx.x * 256;
    f32x4 acc[4][4];
#pragma unroll
    for (int i = 0; i < 4; ++i)
#pragma unroll
        for (int j = 0; j < 4; ++j) acc[i][j] = (f32x4){0.f, 0.f, 0.f, 0.f};

    const short* gp[3];
    int ldsoff[3];
    bool isA[3];
#pragma unroll
    for (int s = 0; s < 3; ++s) {
        int qq = wave * 3 + s;
        bool a = qq < 8;
        int r = (a ? qq : qq - 8) * 16 + (lane >> 2);
        int sc = (((lane & 3) ^ ((r >> 1) & 3)) << 3);
        gp[s] = a ? (A + (size_t)(m0 + r) * K + sc)
                  : (BT + (size_t)(n0 + r) * K + sc);
        ldsoff[s] = (a ? qq : (qq - 8)) * 512;
        isA[s] = a;
    }
    int nk = K >> 5;
    auto stage = [&](int buf) {
#pragma unroll
        for (int s = 0; s < 3; ++s) {
            short* l = isA[s] ? &Asb[buf * 4096 + ldsoff[s]]
                              : &Bsb[buf * 8192 + ldsoff[s]];
            gload16(gp[s], l);
            gp[s] += 32;
        }
    };
    stage(0);
    stage(1);

    int lr = lane & 15, g = lane >> 4;

#define W8_STEP(KT, BUF)                                                          \
    {                                                                             \
        __builtin_amdgcn_sched_barrier(0);                                        \
        if ((KT) + 1 < nk) {                                                      \
            asm volatile("s_waitcnt vmcnt(3)" ::: "memory");                      \
        } else {                                                                  \
            asm volatile("s_waitcnt vmcnt(0)" ::: "memory");                      \
        }                                                                         \
        __builtin_amdgcn_sched_barrier(0);                                        \
        __builtin_amdgcn_s_barrier();                                             \
        if ((KT) + 2 < nk) stage(((BUF) + 2) % 3);                                \
        bf16x8 af[4], bfr[4];                                                     \
        _Pragma("unroll") for (int i = 0; i < 4; ++i) {                           \
            int row = wrM * 64 + i * 16 + lr;                                     \
            af[i] = *(const bf16x8*)&Asb[(BUF) * 4096 + row * 32 +                \
                                         ((g ^ ((row >> 1) & 3)) << 3)];          \
        }                                                                         \
        _Pragma("unroll") for (int j = 0; j < 4; ++j) {                           \
            int row = wcN * 64 + j * 16 + lr;                                     \
            bfr[j] = *(const bf16x8*)&Bsb[(BUF) * 8192 + row * 32 +               \
                                          ((g ^ ((row >> 1) & 3)) << 3)];         \
        }                                                                         \
        _Pragma("unroll") for (int i = 0; i < 4; ++i)                             \
            _Pragma("unroll") for (int j = 0; j < 4; ++j)                         \
                acc[i][j] = __builtin_amdgcn_mfma_f32_16x16x32_bf16(              \
                    af[i], bfr[j], acc[i][j], 0, 0, 0);                           \
    }

    for (int kt = 0; kt < nk; kt += 3) {
        W8_STEP(kt, 0);
        if (kt + 1 < nk) W8_STEP(kt + 1, 1);
        if (kt + 2 < nk) W8_STEP(kt + 2, 2);
    }
#undef W8_STEP

    int lq = lane >> 4;
    if (mode == 2) {
        short* eb = smem;
        int xhalf = wcN >> 1, half = wcN & 1;
        __syncthreads();
#pragma unroll
        for (int i = 0; i < 4; ++i)
#pragma unroll
            for (int j = 0; j < 2; ++j)
#pragma unroll
                for (int r = 0; r < 4; ++r) {
                    int slot = n0 + wcN * 64 + j * 16 + lr;
                    float a = acc[i][j][r] + bias[slot];
                    float gt = acc[i][j + 2][r] + bias[slot + 32];
                    float ge = gelu_fast(gt);
                    int row = wrM * 64 + i * 16 + lq * 4 + r;
                    int col = xhalf * 64 + half * 32 + j * 16 + lr;
                    eb[row * 136 + col] = f2b(a * ge);
                }
        __syncthreads();
#pragma unroll
        for (int q = 0; q < 4; ++q) {
            int idx = q * 512 + tid;
            int row = idx >> 4, cg = (idx & 15) * 8;
            bf16x8 o = *(bf16x8*)&eb[row * 136 + cg];
            *(bf16x8*)&outB[(size_t)(m0 + row) * 2048 + blockIdx.x * 128 + cg] = o;
        }
        return;
    }
    {
        float* ef = (float*)smem;
#pragma unroll
        for (int h = 0; h < 2; ++h) {
            __syncthreads();
            if (wrM == h) {
#pragma unroll
                for (int i = 0; i < 4; ++i)
#pragma unroll
                    for (int j = 0; j < 4; ++j)
#pragma unroll
                        for (int r = 0; r < 4; ++r)
                            ef[(i * 16 + lq * 4 + r) * 260 + wcN * 64 + j * 16 + lr] =
                                acc[i][j][r];
            }
            __syncthreads();
#pragma unroll
            for (int q = 0; q < 8; ++q) {
                int idx = q * 512 + tid;
                int row = idx >> 6;
                int cq = (idx & 63) * 4;
                float4 v = *(float4*)&ef[row * 260 + cq];
                int nn = n0 + cq;
                if (bias) {
                    float4 b4 = *(const float4*)&bias[nn];
                    v.x += b4.x; v.y += b4.y; v.z += b4.z; v.w += b4.w;
                }
                size_t ig = (size_t)(m0 + h * 64 + row) * N + nn;
                if (addSrcB) {
                    short4v a4 = *(const short4v*)&addSrcB[ig];
                    v.x += b2f(a4[0]); v.y += b2f(a4[1]);
                    v.z += b2f(a4[2]); v.w += b2f(a4[3]);
                }
                short4v o = {f2b(v.x), f2b(v.y), f2b(v.z), f2b(v.w)};
                *(short4v*)&outB[ig] = o;
            }
        }
    }
}

// ---------------- MFMA flash attention, max-free softmax, async-staged K/V.
// Row-sum l via MFMA ones-B. XCD remap + setprio. (R18-verified)
__global__ __launch_bounds__(256, 1) void attn_mfma(const short* __restrict__ qp,
                                                    const short* __restrict__ kp,
                                                    const short* __restrict__ vp,
                                                    short* __restrict__ op,
                                                    int kv_len, int kvBatchRows,
                                                    int qStride, int kvStride) {
    __shared__ __attribute__((aligned(16))) short Kt[64][72];
    __shared__ __attribute__((aligned(16))) short Vt[64][72];
    __shared__ __attribute__((aligned(16))) short Pt[4][2][16][72];
    int tid = threadIdx.x, w = tid >> 6, lane = tid & 63;
    int g = lane >> 4, c = lane & 15;
    int id = blockIdx.x;
    int xcd = id & 7, jj2 = id >> 3;
    int bh = xcd * 8 + (jj2 >> 3);
    int qtile = jj2 & 7;
    int b = bh >> 3, h = bh & 7;
    int q0 = qtile * 128 + w * 16;

    const float QS = 0.125f * 1.44269504f;
    bf16x8 qa[2][2];
#pragma unroll
    for (int qi = 0; qi < 2; ++qi) {
        const short* qbase = qp + ((size_t)(b * 1024 + q0 + qi * 64 + c)) * qStride + h * 64;
        bf16x8 qr0 = *(const bf16x8*)(qbase + g * 8);
        bf16x8 qr1 = *(const bf16x8*)(qbase + 32 + g * 8);
#pragma unroll
        for (int j = 0; j < 8; ++j) {
            qa[qi][0][j] = f2b(b2f(qr0[j]) * QS);
            qa[qi][1][j] = f2b(b2f(qr1[j]) * QS);
        }
    }
    bf16x8 vones;
#pragma unroll
    for (int j = 0; j < 8; ++j) vones[j] = (short)0x3F80;  // bf16 1.0

    f32x4 oac[2][4], oacl[2];
#pragma unroll
    for (int qi = 0; qi < 2; ++qi) {
#pragma unroll
        for (int dt = 0; dt < 4; ++dt) oac[qi][dt] = (f32x4){0.f, 0.f, 0.f, 0.f};
        oacl[qi] = (f32x4){0.f, 0.f, 0.f, 0.f};
    }

    int skey = tid & 63, sd0 = (tid >> 6) * 16;
    int ntile = (kv_len + 63) >> 6;
    size_t kvbase = (size_t)b * kvBatchRows;

    bf16x8 k0, k1, v0, v1;
    {
        int krow = skey < kv_len ? skey : kv_len - 1;
        const short* kpp = kp + (kvbase + krow) * kvStride + h * 64 + sd0;
        const short* vpp = vp + (kvbase + krow) * kvStride + h * 64 + sd0;
        k0 = *(const bf16x8*)kpp; k1 = *(const bf16x8*)(kpp + 8);
        v0 = *(const bf16x8*)vpp; v1 = *(const bf16x8*)(vpp + 8);
    }

    for (int kt = 0; kt < ntile; ++kt) {
        __syncthreads();
        *(bf16x8*)&Kt[skey][sd0] = k0;
        *(bf16x8*)&Kt[skey][sd0 + 8] = k1;
#pragma unroll
        for (int j = 0; j < 8; ++j) {
            Vt[sd0 + j][skey] = v0[j];
            Vt[sd0 + 8 + j][skey] = v1[j];
        }
        __syncthreads();
        if (kt + 1 < ntile) {
            int krow = (kt + 1) * 64 + skey;
            if (krow >= kv_len) krow = kv_len - 1;
            const short* kpp = kp + (kvbase + krow) * kvStride + h * 64 + sd0;
            const short* vpp = vp + (kvbase + krow) * kvStride + h * 64 + sd0;
            k0 = *(const bf16x8*)kpp; k1 = *(const bf16x8*)(kpp + 8);
            v0 = *(const bf16x8*)vpp; v1 = *(const bf16x8*)(vpp + 8);
        }

        f32x4 s[2][4];
        __builtin_amdgcn_s_setprio(1);
#pragma unroll
        for (int nt = 0; nt < 4; ++nt) {
            bf16x8 kb0 = *(const bf16x8*)&Kt[nt * 16 + c][g * 8];
            bf16x8 kb1 = *(const bf16x8*)&Kt[nt * 16 + c][32 + g * 8];
#pragma unroll
            for (int qi = 0; qi < 2; ++qi) {
                s[qi][nt] = __builtin_amdgcn_mfma_f32_16x16x32_bf16(
                    qa[qi][0], kb0, (f32x4){0.f, 0.f, 0.f, 0.f}, 0, 0, 0);
                s[qi][nt] = __builtin_amdgcn_mfma_f32_16x16x32_bf16(
                    qa[qi][1], kb1, s[qi][nt], 0, 0, 0);
            }
        }
        __builtin_amdgcn_s_setprio(0);
        if (kt * 64 + 64 > kv_len) {
#pragma unroll
            for (int nt = 0; nt < 4; ++nt) {
                bool valid = kt * 64 + nt * 16 + c < kv_len;
#pragma unroll
                for (int qi = 0; qi < 2; ++qi)
#pragma unroll
                    for (int r = 0; r < 4; ++r)
                        s[qi][nt][r] = valid ? exp2f(s[qi][nt][r]) : 0.f;
            }
        } else {
#pragma unroll
            for (int nt = 0; nt < 4; ++nt)
#pragma unroll
                for (int qi = 0; qi < 2; ++qi)
#pragma unroll
                    for (int r = 0; r < 4; ++r)
                        s[qi][nt][r] = exp2f(s[qi][nt][r]);
        }

        bf16x8 pa[2][2];
#pragma unroll
        for (int qi = 0; qi < 2; ++qi) {
#pragma unroll
            for (int nt = 0; nt < 4; ++nt)
#pragma unroll
                for (int r = 0; r < 4; ++r)
                    Pt[w][qi][4 * g + r][nt * 16 + c] = f2b(s[qi][nt][r]);
        }
#pragma unroll
        for (int qi = 0; qi < 2; ++qi) {
            pa[qi][0] = *(const bf16x8*)&Pt[w][qi][c][g * 8];
            pa[qi][1] = *(const bf16x8*)&Pt[w][qi][c][32 + g * 8];
        }
        __builtin_amdgcn_s_setprio(1);
#pragma unroll
        for (int dt = 0; dt < 4; ++dt) {
            bf16x8 vb0 = *(const bf16x8*)&Vt[dt * 16 + c][g * 8];
            bf16x8 vb1 = *(const bf16x8*)&Vt[dt * 16 + c][32 + g * 8];
#pragma unroll
            for (int qi = 0; qi < 2; ++qi) {
                oac[qi][dt] = __builtin_amdgcn_mfma_f32_16x16x32_bf16(pa[qi][0], vb0, oac[qi][dt], 0, 0, 0);
                oac[qi][dt] = __builtin_amdgcn_mfma_f32_16x16x32_bf16(pa[qi][1], vb1, oac[qi][dt], 0, 0, 0);
            }
        }
#pragma unroll
        for (int qi = 0; qi < 2; ++qi) {
            oacl[qi] = __builtin_amdgcn_mfma_f32_16x16x32_bf16(pa[qi][0], vones, oacl[qi], 0, 0, 0);
            oacl[qi] = __builtin_amdgcn_mfma_f32_16x16x32_bf16(pa[qi][1], vones, oacl[qi], 0, 0, 0);
        }
        __builtin_amdgcn_s_setprio(0);
    }

#pragma unroll
    for (int qi = 0; qi < 2; ++qi)
#pragma unroll
        for (int r = 0; r < 4; ++r) {
            float inv = 1.f / oacl[qi][r];
            short* orow = op + ((size_t)(b * 1024 + q0 + qi * 64 + 4 * g + r)) * 512 + h * 64;
#pragma unroll
            for (int dt = 0; dt < 4; ++dt)
                orow[dt * 16 + c] = f2b(oac[qi][dt][r] * inv);
        }
}

extern "C" void kernel_launch(void* const* d_in, const int* in_sizes, int n_in,
                              void* d_out, int out_size, void* d_ws, size_t ws_size,
                              hipStream_t stream) {
    (void)in_sizes; (void)n_in; (void)out_size; (void)ws_size;
    const float* q_in = (const float*)d_in[0];
    const float* kv_in = (const float*)d_in[1];
    const float* gn_g = (const float*)d_in[2];
    const float* gn_b = (const float*)d_in[3];
    const float* ln2_g = (const float*)d_in[4];
    const float* ln2_b = (const float*)d_in[5];
    const float* ln3_g = (const float*)d_in[6];
    const float* ln3_b = (const float*)d_in[7];
    const float* ln4_g = (const float*)d_in[8];
    const float* ln4_b = (const float*)d_in[9];
    const float* fc_in_w = (const float*)d_in[10];
    const float* fc_in_b = (const float*)d_in[11];
    const float* fc_out_w = (const float*)d_in[12];
    const float* fc_out_b = (const float*)d_in[13];
    const float* a1_qw = (const float*)d_in[14];
    const float* a1_kw = (const float*)d_in[15];
    const float* a1_vw = (const float*)d_in[16];
    const float* a1_ow = (const float*)d_in[17];
    const float* a1_ob = (const float*)d_in[18];
    const float* a2_qw = (const float*)d_in[19];
    const float* a2_kw = (const float*)d_in[20];
    const float* a2_vw = (const float*)d_in[21];
    const float* a2_ow = (const float*)d_in[22];
    const float* a2_ob = (const float*)d_in[23];
    const float* ffp_w = (const float*)d_in[24];
    const float* ffp_b = (const float*)d_in[25];
    const float* ffo_w = (const float*)d_in[26];
    const float* ffo_b = (const float*)d_in[27];
    float* out = (float*)d_out;

    char* p = (char*)d_ws;
    auto alloc = [&](size_t n) {
        char* r = p;
        p += (n + 255) & ~(size_t)255;
        return r;
    };
    short* wt_fci = (short*)alloc((size_t)512 * 512 * 2);
    short* wt_fco = (short*)alloc((size_t)512 * 512 * 2);
    short* wt_qkv = (short*)alloc((size_t)1536 * 512 * 2);
    short* wt_a1o = (short*)alloc((size_t)512 * 512 * 2);
    short* wt_a2q = (short*)alloc((size_t)512 * 512 * 2);
    short* wt_kv2 = (short*)alloc((size_t)1024 * 1024 * 2);
    short* wt_a2o = (short*)alloc((size_t)512 * 512 * 2);
    short* wt_ffp = (short*)alloc((size_t)4096 * 512 * 2);
    short* wt_ffo = (short*)alloc((size_t)512 * 2048 * 2);
    float* biasP = (float*)alloc((size_t)4096 * 4);
    short* xb = (short*)alloc((size_t)8192 * 512 * 2);
    short* tb = (short*)alloc((size_t)8192 * 512 * 2);
    short* qkvbuf = (short*)alloc((size_t)8192 * 1536 * 2);
    short* qbuf = (short*)alloc((size_t)8192 * 512 * 2);
    short* kvpbuf = (short*)alloc((size_t)616 * 1024 * 2);
    short* obuf = (short*)alloc((size_t)8192 * 512 * 2);
    short* kvb = (short*)alloc((size_t)616 * 1024 * 2);
    short* ggb = (short*)alloc((size_t)8192 * 2048 * 2);
    float* gnsc = (float*)alloc((size_t)8 * 512 * 4);
    float* gnsh = (float*)alloc((size_t)8 * 512 * 4);

    PrepArgs pa;
    pa.src[0] = fc_in_w;  pa.dst[0] = wt_fci;
    pa.src[1] = fc_out_w; pa.dst[1] = wt_fco;
    pa.src[2] = a1_qw;    pa.dst[2] = wt_qkv;
    pa.src[3] = a1_kw;    pa.dst[3] = wt_qkv + (size_t)512 * 512;
    pa.src[4] = a1_vw;    pa.dst[4] = wt_qkv + (size_t)1024 * 512;
    pa.src[5] = a1_ow;    pa.dst[5] = wt_a1o;
    pa.src[6] = a2_qw;    pa.dst[6] = wt_a2q;
    pa.src[7] = a2_kw;    pa.dst[7] = wt_kv2;
    pa.src[8] = a2_vw;    pa.dst[8] = wt_kv2 + (size_t)512 * 1024;
    pa.src[9] = a2_ow;    pa.dst[9] = wt_a2o;
    pa.src[10] = ffp_w;   pa.dst[10] = wt_ffp;
    pa.src[11] = ffo_w;   pa.dst[11] = wt_ffo;
    pa.kv = kv_in; pa.kvb = kvb; pa.fb = ffp_b; pa.bp = biasP;
    pa.qin = q_in; pa.gng = gn_g; pa.gnb = gn_b; pa.gnsc = gnsc; pa.gnsh = gnsh;
    prep<<<6724, 256, 0, stream>>>(pa);

    gn_apply<<<256, 256, 0, stream>>>(q_in, gnsc, gnsh, tb);
    gemm_gl<128><<<dim3(4, 64), 256, 0, stream>>>(
        tb, wt_fci, 8192, 512, 512, fc_in_b, nullptr, xb, nullptr, nullptr, 0);
    ln_rows<<<2048, 256, 0, stream>>>(xb, ln2_g, ln2_b, tb);
    gemm_gl<128><<<dim3(12, 64), 256, 0, stream>>>(
        tb, wt_qkv, 8192, 1536, 512, nullptr, nullptr, qkvbuf, nullptr, nullptr, 0);
    attn_mfma<<<512, 256, 0, stream>>>(qkvbuf, qkvbuf + 512, qkvbuf + 1024, obuf,
                                       1024, 1024, 1536, 1536);
    gemm_gl<128><<<dim3(4, 64), 256, 0, stream>>>(
        obuf, wt_a1o, 8192, 512, 512, a1_ob, xb, xb, nullptr, nullptr, 0);
    ln_rows<<<2048, 256, 0, stream>>>(xb, ln3_g, ln3_b, tb);
    // a2q + kv2 merged: kv2's 80 blocks ride along with a2q's 256.
    gemm_dual<<<336, 256, 0, stream>>>(tb, wt_a2q, qbuf, 8192, 512, 512,
                                       kvb, wt_kv2, kvpbuf, 616, 1024, 1024);
    attn_mfma<<<512, 256, 0, stream>>>(qbuf, kvpbuf, kvpbuf + 512, obuf,
                                       77, 77, 512, 1024);
    gemm_gl<128><<<dim3(4, 64), 256, 0, stream>>>(
        obuf, wt_a2o, 8192, 512, 512, a2_ob, xb, xb, nullptr, nullptr, 0);
    ln_rows<<<2048, 256, 0, stream>>>(xb, ln4_g, ln4_b, tb);
    gemm256w<<<dim3(16, 64), 512, 0, stream>>>(tb, wt_ffp, 8192, 4096, 512,
                                               biasP, nullptr, ggb, 2);
    gemm_gl<128><<<dim3(4, 64), 256, 0, stream>>>(
        ggb, wt_ffo, 8192, 512, 2048, ffo_b, xb, tb, nullptr, nullptr, 0);
    gemm_gl<128><<<dim3(4, 64), 256, 0, stream>>>(
        tb, wt_fco, 8192, 512, 512, fc_out_b, nullptr, nullptr, q_in, out, 1);
}